// Round 10
// baseline (451.174 us; speedup 1.0000x reference)
//
#include <hip/hip_runtime.h>
#include <stdint.h>

#define NN 50000
#define NE 800000
#define FD 64
#define HD 128

typedef __attribute__((ext_vector_type(8))) short short8;   // 8 bf16 (4 VGPRs)
typedef __attribute__((ext_vector_type(4))) float f32x4;    // MFMA acc

#define AS1 __attribute__((address_space(1)))
#define AS3 __attribute__((address_space(3)))

// ---------- bf16 helpers ----------
__device__ __forceinline__ float bflo(unsigned int v) {
    union { unsigned int u; float f; } c; c.u = v << 16; return c.f;
}
__device__ __forceinline__ float bfhi(unsigned int v) {
    union { unsigned int u; float f; } c; c.u = v & 0xffff0000u; return c.f;
}
__device__ __forceinline__ unsigned short f2bf(float f) {
    union { float f; unsigned int u; } c; c.f = f;
    unsigned int u = c.u;
    return (unsigned short)((u + 0x7fffu + ((u >> 16) & 1u)) >> 16);
}
__device__ __forceinline__ unsigned int pack2(float a, float b) {
    return (unsigned int)f2bf(a) | ((unsigned int)f2bf(b) << 16);
}

// ---------- weight transpose/convert/swizzle: W[K][C] fp32 -> Wt[c][K] bf16 ----------
// 16B-granule XOR swizzle: (k,c) -> T[c*K + ((k>>3) ^ (c & (K/8-1)))*8 + (k&7)]
__global__ void wt_k(const float* __restrict__ w0, const float* __restrict__ w1,
                     const float* __restrict__ w2, const float* __restrict__ w3,
                     const float* __restrict__ w4, const float* __restrict__ w5,
                     const float* __restrict__ w6,
                     unsigned short* __restrict__ t0, unsigned short* __restrict__ t1,
                     unsigned short* __restrict__ t2, unsigned short* __restrict__ t3,
                     unsigned short* __restrict__ t4, unsigned short* __restrict__ t5,
                     unsigned short* __restrict__ t6)
{
    int b = blockIdx.x;
    const float* W; unsigned short* T; int K, C;
    if      (b <  32) { W = w0; T = t0; K =  64; C = 128; }
    else if (b <  96) { W = w1; T = t1; K = 128; C = 128; b -= 32; }
    else if (b < 160) { W = w2; T = t2; K = 128; C = 128; b -= 96; }
    else if (b < 224) { W = w3; T = t3; K = 128; C = 128; b -= 160; }
    else if (b < 288) { W = w4; T = t4; K = 128; C = 128; b -= 224; }
    else if (b < 352) { W = w5; T = t5; K = 128; C = 128; b -= 288; }
    else              { W = w6; T = t6; K = 128; C =  64; b -= 352; }
    int e = b * 256 + threadIdx.x;
    int k, c;
    if (C == 128) { k = e >> 7; c = e & 127; } else { k = e >> 6; c = e & 63; }
    int gmask = (K >> 3) - 1;
    int gsw = (k >> 3) ^ (c & gmask);
    T[c * K + gsw * 8 + (k & 7)] = f2bf(W[e]);
}

__global__ void scanB_k(int* __restrict__ bsum, int nb) {
    __shared__ int sh[256];
    int t = threadIdx.x;
    int v = (t < nb) ? bsum[t] : 0;
    sh[t] = v; __syncthreads();
    for (int d = 1; d < 256; d <<= 1) {
        int x = (t >= d) ? sh[t - d] : 0; __syncthreads();
        sh[t] += x; __syncthreads();
    }
    if (t < nb) bsum[t] = sh[t] - v;
}

// ---------- MFMA GEMM device body (block id passed in) ----------
template <int K, int COLS, int EPI, bool BIAS, bool RSCALE, bool A_F32, bool OUT_F32>
__device__ __forceinline__ void mgemm_dev(
    int bid,
    const void* __restrict__ Av,
    const unsigned short* __restrict__ Wt,
    const float* __restrict__ bias,
    const float* __restrict__ dinv,
    void* __restrict__ outv, int nrows)
{
    constexpr int NB = COLS / 16;
    constexpr int KC = K / 32;
    constexpr int GMASK = (K >> 3) - 1;
    __shared__ __align__(16) unsigned char Ws8[COLS * K * 2];

    const int tid = threadIdx.x;
    const int wave = tid >> 6;
    const int lane = tid & 63;

    {
        constexpr int ROUNDS = COLS * K * 2 / 4096;
        const int gb = wave * 1024 + lane * 16;
        const int lb = wave * 1024;
        #pragma unroll
        for (int r = 0; r < ROUNDS; r++) {
            __builtin_amdgcn_global_load_lds(
                (const AS1 unsigned int*)((const unsigned char*)Wt + r * 4096 + gb),
                (AS3 unsigned int*)(Ws8 + r * 4096 + lb),
                16, 0, 0);
        }
    }

    const int m = lane & 15;
    const int q = lane >> 4;
    const int row0 = bid * 64 + wave * 16;

    f32x4 acc[NB];
    #pragma unroll
    for (int i = 0; i < NB; i++) acc[i] = (f32x4){0.f, 0.f, 0.f, 0.f};

    const bool arow_ok = !A_F32 || (row0 + m) < nrows;

    short8 af[KC];
    #pragma unroll
    for (int kc = 0; kc < KC; kc++) {
        if constexpr (A_F32) {
            const float* arowf = (const float*)Av + (size_t)(row0 + m) * K + q * 8 + kc * 32;
            float4 lo = make_float4(0.f, 0.f, 0.f, 0.f), hi = lo;
            if (arow_ok) { lo = *(const float4*)arowf; hi = *(const float4*)(arowf + 4); }
            af[kc][0] = (short)f2bf(lo.x); af[kc][1] = (short)f2bf(lo.y);
            af[kc][2] = (short)f2bf(lo.z); af[kc][3] = (short)f2bf(lo.w);
            af[kc][4] = (short)f2bf(hi.x); af[kc][5] = (short)f2bf(hi.y);
            af[kc][6] = (short)f2bf(hi.z); af[kc][7] = (short)f2bf(hi.w);
        } else {
            const unsigned short* arow = (const unsigned short*)Av + (size_t)(row0 + m) * K + q * 8 + kc * 32;
            af[kc] = *(const short8*)arow;
        }
    }
    __syncthreads();

    #pragma unroll
    for (int kc = 0; kc < KC; kc++) {
        #pragma unroll
        for (int nb = 0; nb < NB; nb++) {
            const int c = nb * 16 + m;
            const int gsw = (kc * 4 + q) ^ (c & GMASK);
            short8 bf = *(const short8*)&Ws8[(c * K + gsw * 8) * 2];
            acc[nb] = __builtin_amdgcn_mfma_f32_16x16x32_bf16(af[kc], bf, acc[nb], 0, 0, 0);
        }
    }

    float bv[NB];
    #pragma unroll
    for (int nb = 0; nb < NB; nb++) bv[nb] = BIAS ? bias[nb * 16 + m] : 0.f;

    #pragma unroll
    for (int r = 0; r < 4; r++) {
        int row = row0 + q * 4 + r;
        if (row < nrows) {
            float sc = RSCALE ? dinv[row] : 1.f;
            #pragma unroll
            for (int nb = 0; nb < NB; nb++) {
                float t = acc[nb][r];
                if (RSCALE) t *= sc;
                t += bv[nb];
                if (EPI == 1) t = fmaxf(t, 0.f);
                if (EPI == 2) t = 1.f / (1.f + __expf(-t));
                if constexpr (OUT_F32) {
                    ((float*)outv)[(size_t)row * COLS + nb * 16 + m] = t;
                } else {
                    ((unsigned short*)outv)[(size_t)row * COLS + nb * 16 + m] = f2bf(t);
                }
            }
        }
    }
}

// plain mgemm wrapper
template <int K, int COLS, int EPI, bool BIAS, bool RSCALE, bool A_F32, bool OUT_F32>
__global__ __launch_bounds__(256) void mgemm_k(
    const void* __restrict__ Av, const unsigned short* __restrict__ Wt,
    const float* __restrict__ bias, const float* __restrict__ dinv,
    void* __restrict__ outv, int nrows)
{
    mgemm_dev<K, COLS, EPI, BIAS, RSCALE, A_F32, OUT_F32>(blockIdx.x, Av, Wt, bias, dinv, outv, nrows);
}

// ---------- FUSED agg + gemm ----------
// Phase 1: block aggregates its 64 nodes (half-wave per node, 8 nodes each),
//          h = relu(dinv*(self+sum)+abias) -> LDS tile (row stride 136 ushorts).
// Phase 2: mgemm body with A-frags from LDS h.
// W stages via global_load_lds concurrent with phase 1; one barrier covers both.
template <int GEPI, bool GBIAS, bool GRSCALE, bool GOUT_F32>
__global__ __launch_bounds__(256) void agggemm_k(
    const uint2* __restrict__ hws,          // [N][32] gather source
    const int* __restrict__ off, const int* __restrict__ bsum,
    const unsigned short* __restrict__ csr,
    const float* __restrict__ dinv, const float* __restrict__ abias,
    const unsigned short* __restrict__ Wt,  // [128][128] swizzled bf16
    const float* __restrict__ gbias,
    void* __restrict__ outv, int n)
{
    constexpr int K = 128, COLS = 128;
    constexpr int NB = COLS / 16, KC = K / 32, GMASK = (K >> 3) - 1;
    constexpr int HP = 136;  // padded h row stride (ushorts), 272 B
    __shared__ __align__(16) unsigned char Ws8[COLS * K * 2];
    __shared__ __align__(16) unsigned short h[64 * HP];

    const int tid = threadIdx.x;
    const int wave = tid >> 6;
    const int lane = tid & 63;

    // stage W -> LDS (completes by the barrier below)
    {
        constexpr int ROUNDS = COLS * K * 2 / 4096;
        const int gb = wave * 1024 + lane * 16;
        const int lb = wave * 1024;
        #pragma unroll
        for (int r = 0; r < ROUNDS; r++) {
            __builtin_amdgcn_global_load_lds(
                (const AS1 unsigned int*)((const unsigned char*)Wt + r * 4096 + gb),
                (AS3 unsigned int*)(Ws8 + r * 4096 + lb),
                16, 0, 0);
        }
    }

    // phase 1: aggregation into LDS h
    {
        const int hw = tid >> 5;     // half-wave 0..7
        const int l  = tid & 31;
        const float4 bv = *(const float4*)(abias + 4 * l);
        #pragma unroll 1
        for (int i = 0; i < 8; i++) {
            const int nl = hw * 8 + i;
            const int node = blockIdx.x * 64 + nl;
            uint2 o;
            if (node < n) {
                uint2 v = hws[node * 32 + l];  // self-loop
                float s0 = bflo(v.x), s1 = bfhi(v.x), s2 = bflo(v.y), s3 = bfhi(v.y);
                int b = off[node] + bsum[node >> 8];
                int e = (node + 1 < n) ? (off[node + 1] + bsum[(node + 1) >> 8]) : NE;
                int j = b;
                for (; j + 8 <= e; j += 8) {
                    uint2 t[8];
                    #pragma unroll
                    for (int u = 0; u < 8; u++) t[u] = hws[(int)csr[j + u] * 32 + l];
                    #pragma unroll
                    for (int u = 0; u < 8; u++) {
                        s0 += bflo(t[u].x); s1 += bfhi(t[u].x);
                        s2 += bflo(t[u].y); s3 += bfhi(t[u].y);
                    }
                }
                for (; j < e; j++) {
                    uint2 t = hws[(int)csr[j] * 32 + l];
                    s0 += bflo(t.x); s1 += bfhi(t.x);
                    s2 += bflo(t.y); s3 += bfhi(t.y);
                }
                float di = dinv[node];
                float r0 = fmaxf(fmaf(di, s0, bv.x), 0.f);
                float r1 = fmaxf(fmaf(di, s1, bv.y), 0.f);
                float r2 = fmaxf(fmaf(di, s2, bv.z), 0.f);
                float r3 = fmaxf(fmaf(di, s3, bv.w), 0.f);
                o.x = pack2(r0, r1); o.y = pack2(r2, r3);
            } else {
                o.x = 0u; o.y = 0u;
            }
            *(uint2*)&h[nl * HP + l * 4] = o;
        }
    }
    __syncthreads();

    // phase 2: gemm, A-frags from LDS h
    const int m = lane & 15;
    const int q = lane >> 4;
    const int row0 = blockIdx.x * 64 + wave * 16;

    f32x4 acc[NB];
    #pragma unroll
    for (int i = 0; i < NB; i++) acc[i] = (f32x4){0.f, 0.f, 0.f, 0.f};

    short8 af[KC];
    #pragma unroll
    for (int kc = 0; kc < KC; kc++)
        af[kc] = *(const short8*)&h[(wave * 16 + m) * HP + kc * 32 + q * 8];

    #pragma unroll
    for (int kc = 0; kc < KC; kc++) {
        #pragma unroll
        for (int nb = 0; nb < NB; nb++) {
            const int c = nb * 16 + m;
            const int gsw = (kc * 4 + q) ^ (c & GMASK);
            short8 bf = *(const short8*)&Ws8[(c * K + gsw * 8) * 2];
            acc[nb] = __builtin_amdgcn_mfma_f32_16x16x32_bf16(af[kc], bf, acc[nb], 0, 0, 0);
        }
    }

    float bv2[NB];
    #pragma unroll
    for (int nb = 0; nb < NB; nb++) bv2[nb] = GBIAS ? gbias[nb * 16 + m] : 0.f;

    #pragma unroll
    for (int r = 0; r < 4; r++) {
        int row = row0 + q * 4 + r;
        if (row < n) {
            float sc = GRSCALE ? dinv[row] : 1.f;
            #pragma unroll
            for (int nb = 0; nb < NB; nb++) {
                float t = acc[nb][r];
                if (GRSCALE) t *= sc;
                t += bv2[nb];
                if (GEPI == 1) t = fmaxf(t, 0.f);
                if (GEPI == 2) t = 1.f / (1.f + __expf(-t));
                if constexpr (GOUT_F32) {
                    ((float*)outv)[(size_t)row * COLS + nb * 16 + m] = t;
                } else {
                    ((unsigned short*)outv)[(size_t)row * COLS + nb * 16 + m] = f2bf(t);
                }
            }
        }
    }
}

// ---------- K1: enc1-mgemm ∥ dst-histogram ----------
__global__ __launch_bounds__(256) void k1_k(
    const float* __restrict__ x, const unsigned short* __restrict__ t0,
    const float* __restrict__ enc_b1, unsigned short* __restrict__ bufA,
    const int* __restrict__ dst, int* __restrict__ cnt, int gb)
{
    if ((int)blockIdx.x < gb) {
        mgemm_dev<64, 128, 1, true, false, true, false>(blockIdx.x, x, t0, enc_b1, nullptr, bufA, NN);
    } else {
        int g = (blockIdx.x - gb) * 256 + threadIdx.x;
        if (g < NE) atomicAdd(&cnt[dst[g]], 1);
    }
}

// ---------- K2: enc2-mgemm ∥ scanA ----------
__global__ __launch_bounds__(256) void k2_k(
    const unsigned short* __restrict__ bufA, const unsigned short* __restrict__ t1,
    const float* __restrict__ enc_b2, unsigned short* __restrict__ bufB,
    const int* __restrict__ cnt, int* __restrict__ off, int* __restrict__ bsum,
    float* __restrict__ dinv, int gb)
{
    if ((int)blockIdx.x < gb) {
        mgemm_dev<128, 128, 0, true, false, false, false>(blockIdx.x, bufA, t1, enc_b2, nullptr, bufB, NN);
    } else {
        __shared__ int sh[256];
        int t = threadIdx.x;
        int g = (blockIdx.x - gb) * 256 + t;
        int v = (g < NN) ? cnt[g] : 0;
        if (g < NN) dinv[g] = rsqrtf((float)(v + 1));  // +1 self-loop
        sh[t] = v; __syncthreads();
        for (int d = 1; d < 256; d <<= 1) {
            int x2 = (t >= d) ? sh[t - d] : 0; __syncthreads();
            sh[t] += x2; __syncthreads();
        }
        if (g < NN) off[g] = sh[t] - v;
        if (t == 255) bsum[blockIdx.x - gb] = sh[255];
    }
}

// ---------- K4: conv1-mgemm ∥ CSR fill ----------
__global__ __launch_bounds__(256) void k4_k(
    const unsigned short* __restrict__ bufB, const unsigned short* __restrict__ t2,
    const float* __restrict__ dinv, unsigned short* __restrict__ bufA,
    const int* __restrict__ src, const int* __restrict__ dst,
    const int* __restrict__ off, const int* __restrict__ bsum,
    int* __restrict__ cur, unsigned short* __restrict__ csr, int gb)
{
    if ((int)blockIdx.x < gb) {
        mgemm_dev<128, 128, 0, false, true, false, false>(blockIdx.x, bufB, t2, nullptr, dinv, bufA, NN);
    } else {
        int g = (blockIdx.x - gb) * 256 + threadIdx.x;
        if (g < NE) {
            int d = dst[g];
            int p = atomicAdd(&cur[d], 1);
            csr[off[d] + bsum[d >> 8] + p] = (unsigned short)src[g];
        }
    }
}

// ---------- launch ----------
extern "C" void kernel_launch(void* const* d_in, const int* in_sizes, int n_in,
                              void* d_out, int out_size, void* d_ws, size_t ws_size,
                              hipStream_t stream)
{
    const float* x      = (const float*)d_in[0];
    const int*   ei     = (const int*)d_in[1];
    const float* enc_w1 = (const float*)d_in[2];
    const float* enc_b1 = (const float*)d_in[3];
    const float* enc_w2 = (const float*)d_in[4];
    const float* enc_b2 = (const float*)d_in[5];
    const float* w_c1   = (const float*)d_in[6];
    const float* b_c1   = (const float*)d_in[7];
    const float* w_c2   = (const float*)d_in[8];
    const float* b_c2   = (const float*)d_in[9];
    const float* w_c3   = (const float*)d_in[10];
    const float* b_c3   = (const float*)d_in[11];
    const float* dec_w1 = (const float*)d_in[12];
    const float* dec_b1 = (const float*)d_in[13];
    const float* dec_w2 = (const float*)d_in[14];
    const float* dec_b2 = (const float*)d_in[15];

    const int* src = ei;
    const int* dst = ei + NE;

    const int NP = 50048;  // rows padded to multiple of 64

    char* ws = (char*)d_ws;
    size_t o = 0;
    auto alloc = [&](size_t bytes) -> void* {
        void* p = ws + o;
        o = (o + bytes + 255) & ~(size_t)255;
        return p;
    };
    int*   cnt  = (int*)alloc((size_t)NN * 4);   // cnt and cur adjacent: one memset
    int*   cur  = (int*)alloc((size_t)NN * 4);
    int*   off  = (int*)alloc((size_t)(NN + 1) * 4);
    int*   bsum = (int*)alloc(256 * 4);
    unsigned short* csr = (unsigned short*)alloc((size_t)NE * 2);
    float* dinv = (float*)alloc((size_t)NN * 4);
    unsigned short* bufA = (unsigned short*)alloc((size_t)NP * HD * 2);
    unsigned short* bufB = (unsigned short*)alloc((size_t)NP * HD * 2);
    unsigned short* t0 = (unsigned short*)alloc(64 * 128 * 2);   // enc_w1^T (swizzled)
    unsigned short* t1 = (unsigned short*)alloc(128 * 128 * 2);  // enc_w2^T
    unsigned short* t2 = (unsigned short*)alloc(128 * 128 * 2);  // w_c1^T
    unsigned short* t3 = (unsigned short*)alloc(128 * 128 * 2);  // w_c2^T
    unsigned short* t4 = (unsigned short*)alloc(128 * 128 * 2);  // w_c3^T
    unsigned short* t5 = (unsigned short*)alloc(128 * 128 * 2);  // dec_w1^T
    unsigned short* t6 = (unsigned short*)alloc(128 * 64 * 2);   // dec_w2^T
    (void)ws_size; (void)n_in; (void)in_sizes; (void)out_size;

    // single memset covers cnt + cur (adjacent, 256-aligned)
    hipMemsetAsync(cnt, 0, (size_t)((char*)cur - (char*)cnt) + (size_t)NN * 4, stream);

    const int HB = (NE + 255) / 256;   // 3125 edge blocks
    const int NB_ = (NN + 255) / 256;  // 196 node blocks
    const int GB = NP / 64;            // 782 gemm row-tiles

    // prep chain overlapped with encoder chain via block-range merged kernels
    wt_k<<<384, 256, 0, stream>>>(enc_w1, enc_w2, w_c1, w_c2, w_c3, dec_w1, dec_w2,
                                  t0, t1, t2, t3, t4, t5, t6);
    k1_k<<<GB + HB, 256, 0, stream>>>(x, t0, enc_b1, bufA, dst, cnt, GB);          // enc1 ∥ hist
    k2_k<<<GB + NB_, 256, 0, stream>>>(bufA, t1, enc_b2, bufB, cnt, off, bsum, dinv, GB); // enc2 ∥ scanA
    scanB_k<<<1, 256, 0, stream>>>(bsum, NB_);
    k4_k<<<GB + HB, 256, 0, stream>>>(bufB, t2, dinv, bufA, src, dst, off, bsum, cur, csr, GB); // conv1 ∥ fill

    // fused agg+gemm: agg1+conv2g, agg2+conv3g, agg3+dec1g
    agggemm_k<0, false, true, false><<<GB, 256, 0, stream>>>(
        (const uint2*)bufA, off, bsum, csr, dinv, b_c1, t3, nullptr, bufB, NN);
    agggemm_k<0, false, true, false><<<GB, 256, 0, stream>>>(
        (const uint2*)bufB, off, bsum, csr, dinv, b_c2, t4, nullptr, bufA, NN);
    agggemm_k<1, true, false, false><<<GB, 256, 0, stream>>>(
        (const uint2*)bufA, off, bsum, csr, dinv, b_c3, t5, dec_b1, bufB, NN);
    // decoder layer 2
    mgemm_k<128, 64, 2, true, false, false, true><<<GB, 256, 0, stream>>>(bufB, t6, dec_b2, nullptr, d_out, NN);
}

// Round 11
// 350.751 us; speedup vs baseline: 1.2863x; 1.2863x over previous
//
#include <hip/hip_runtime.h>
#include <stdint.h>

#define NN 50000
#define NE 800000
#define FD 64
#define HD 128

typedef __attribute__((ext_vector_type(8))) short short8;   // 8 bf16 (4 VGPRs)
typedef __attribute__((ext_vector_type(4))) float f32x4;    // MFMA acc

#define AS1 __attribute__((address_space(1)))
#define AS3 __attribute__((address_space(3)))

// ---------- bf16 helpers ----------
__device__ __forceinline__ float bflo(unsigned int v) {
    union { unsigned int u; float f; } c; c.u = v << 16; return c.f;
}
__device__ __forceinline__ float bfhi(unsigned int v) {
    union { unsigned int u; float f; } c; c.u = v & 0xffff0000u; return c.f;
}
__device__ __forceinline__ unsigned short f2bf(float f) {
    union { float f; unsigned int u; } c; c.f = f;
    unsigned int u = c.u;
    return (unsigned short)((u + 0x7fffu + ((u >> 16) & 1u)) >> 16);
}
__device__ __forceinline__ unsigned int pack2(float a, float b) {
    return (unsigned int)f2bf(a) | ((unsigned int)f2bf(b) << 16);
}

// ---------- weight transpose/convert/swizzle: W[K][C] fp32 -> Wt[c][K] bf16 ----------
// 16B-granule XOR swizzle: (k,c) -> T[c*K + ((k>>3) ^ (c & (K/8-1)))*8 + (k&7)]
__global__ void wt_k(const float* __restrict__ w0, const float* __restrict__ w1,
                     const float* __restrict__ w2, const float* __restrict__ w3,
                     const float* __restrict__ w4, const float* __restrict__ w5,
                     const float* __restrict__ w6,
                     unsigned short* __restrict__ t0, unsigned short* __restrict__ t1,
                     unsigned short* __restrict__ t2, unsigned short* __restrict__ t3,
                     unsigned short* __restrict__ t4, unsigned short* __restrict__ t5,
                     unsigned short* __restrict__ t6)
{
    int b = blockIdx.x;
    const float* W; unsigned short* T; int K, C;
    if      (b <  32) { W = w0; T = t0; K =  64; C = 128; }
    else if (b <  96) { W = w1; T = t1; K = 128; C = 128; b -= 32; }
    else if (b < 160) { W = w2; T = t2; K = 128; C = 128; b -= 96; }
    else if (b < 224) { W = w3; T = t3; K = 128; C = 128; b -= 160; }
    else if (b < 288) { W = w4; T = t4; K = 128; C = 128; b -= 224; }
    else if (b < 352) { W = w5; T = t5; K = 128; C = 128; b -= 288; }
    else              { W = w6; T = t6; K = 128; C =  64; b -= 352; }
    int e = b * 256 + threadIdx.x;
    int k, c;
    if (C == 128) { k = e >> 7; c = e & 127; } else { k = e >> 6; c = e & 63; }
    int gmask = (K >> 3) - 1;
    int gsw = (k >> 3) ^ (c & gmask);
    T[c * K + gsw * 8 + (k & 7)] = f2bf(W[e]);
}

__global__ void scanB_k(int* __restrict__ bsum, int nb) {
    __shared__ int sh[256];
    int t = threadIdx.x;
    int v = (t < nb) ? bsum[t] : 0;
    sh[t] = v; __syncthreads();
    for (int d = 1; d < 256; d <<= 1) {
        int x = (t >= d) ? sh[t - d] : 0; __syncthreads();
        sh[t] += x; __syncthreads();
    }
    if (t < nb) bsum[t] = sh[t] - v;
}

// ---------- MFMA GEMM device body (block id passed in) ----------
template <int K, int COLS, int EPI, bool BIAS, bool RSCALE, bool A_F32, bool OUT_F32>
__device__ __forceinline__ void mgemm_dev(
    int bid,
    const void* __restrict__ Av,
    const unsigned short* __restrict__ Wt,
    const float* __restrict__ bias,
    const float* __restrict__ dinv,
    void* __restrict__ outv, int nrows)
{
    constexpr int NB = COLS / 16;
    constexpr int KC = K / 32;
    constexpr int GMASK = (K >> 3) - 1;
    __shared__ __align__(16) unsigned char Ws8[COLS * K * 2];

    const int tid = threadIdx.x;
    const int wave = tid >> 6;
    const int lane = tid & 63;

    {
        constexpr int ROUNDS = COLS * K * 2 / 4096;
        const int gb = wave * 1024 + lane * 16;
        const int lb = wave * 1024;
        #pragma unroll
        for (int r = 0; r < ROUNDS; r++) {
            __builtin_amdgcn_global_load_lds(
                (const AS1 unsigned int*)((const unsigned char*)Wt + r * 4096 + gb),
                (AS3 unsigned int*)(Ws8 + r * 4096 + lb),
                16, 0, 0);
        }
    }

    const int m = lane & 15;
    const int q = lane >> 4;
    const int row0 = bid * 64 + wave * 16;

    f32x4 acc[NB];
    #pragma unroll
    for (int i = 0; i < NB; i++) acc[i] = (f32x4){0.f, 0.f, 0.f, 0.f};

    const bool arow_ok = !A_F32 || (row0 + m) < nrows;

    short8 af[KC];
    #pragma unroll
    for (int kc = 0; kc < KC; kc++) {
        if constexpr (A_F32) {
            const float* arowf = (const float*)Av + (size_t)(row0 + m) * K + q * 8 + kc * 32;
            float4 lo = make_float4(0.f, 0.f, 0.f, 0.f), hi = lo;
            if (arow_ok) { lo = *(const float4*)arowf; hi = *(const float4*)(arowf + 4); }
            af[kc][0] = (short)f2bf(lo.x); af[kc][1] = (short)f2bf(lo.y);
            af[kc][2] = (short)f2bf(lo.z); af[kc][3] = (short)f2bf(lo.w);
            af[kc][4] = (short)f2bf(hi.x); af[kc][5] = (short)f2bf(hi.y);
            af[kc][6] = (short)f2bf(hi.z); af[kc][7] = (short)f2bf(hi.w);
        } else {
            const unsigned short* arow = (const unsigned short*)Av + (size_t)(row0 + m) * K + q * 8 + kc * 32;
            af[kc] = *(const short8*)arow;
        }
    }
    __syncthreads();

    #pragma unroll
    for (int kc = 0; kc < KC; kc++) {
        #pragma unroll
        for (int nb = 0; nb < NB; nb++) {
            const int c = nb * 16 + m;
            const int gsw = (kc * 4 + q) ^ (c & GMASK);
            short8 bf = *(const short8*)&Ws8[(c * K + gsw * 8) * 2];
            acc[nb] = __builtin_amdgcn_mfma_f32_16x16x32_bf16(af[kc], bf, acc[nb], 0, 0, 0);
        }
    }

    float bv[NB];
    #pragma unroll
    for (int nb = 0; nb < NB; nb++) bv[nb] = BIAS ? bias[nb * 16 + m] : 0.f;

    #pragma unroll
    for (int r = 0; r < 4; r++) {
        int row = row0 + q * 4 + r;
        if (row < nrows) {
            float sc = RSCALE ? dinv[row] : 1.f;
            #pragma unroll
            for (int nb = 0; nb < NB; nb++) {
                float t = acc[nb][r];
                if (RSCALE) t *= sc;
                t += bv[nb];
                if (EPI == 1) t = fmaxf(t, 0.f);
                if (EPI == 2) t = 1.f / (1.f + __expf(-t));
                if constexpr (OUT_F32) {
                    ((float*)outv)[(size_t)row * COLS + nb * 16 + m] = t;
                } else {
                    ((unsigned short*)outv)[(size_t)row * COLS + nb * 16 + m] = f2bf(t);
                }
            }
        }
    }
}

// plain mgemm wrapper
template <int K, int COLS, int EPI, bool BIAS, bool RSCALE, bool A_F32, bool OUT_F32>
__global__ __launch_bounds__(256) void mgemm_k(
    const void* __restrict__ Av, const unsigned short* __restrict__ Wt,
    const float* __restrict__ bias, const float* __restrict__ dinv,
    void* __restrict__ outv, int nrows)
{
    mgemm_dev<K, COLS, EPI, BIAS, RSCALE, A_F32, OUT_F32>(blockIdx.x, Av, Wt, bias, dinv, outv, nrows);
}

// ---------- K1: enc1-mgemm ∥ dst-histogram ----------
__global__ __launch_bounds__(256) void k1_k(
    const float* __restrict__ x, const unsigned short* __restrict__ t0,
    const float* __restrict__ enc_b1, unsigned short* __restrict__ bufA,
    const int* __restrict__ dst, int* __restrict__ cnt, int gb)
{
    if ((int)blockIdx.x < gb) {
        mgemm_dev<64, 128, 1, true, false, true, false>(blockIdx.x, x, t0, enc_b1, nullptr, bufA, NN);
    } else {
        int g = (blockIdx.x - gb) * 256 + threadIdx.x;
        if (g < NE) atomicAdd(&cnt[dst[g]], 1);
    }
}

// ---------- K2: enc2-mgemm ∥ scanA ----------
__global__ __launch_bounds__(256) void k2_k(
    const unsigned short* __restrict__ bufA, const unsigned short* __restrict__ t1,
    const float* __restrict__ enc_b2, unsigned short* __restrict__ bufB,
    const int* __restrict__ cnt, int* __restrict__ off, int* __restrict__ bsum,
    float* __restrict__ dinv, int gb)
{
    if ((int)blockIdx.x < gb) {
        mgemm_dev<128, 128, 0, true, false, false, false>(blockIdx.x, bufA, t1, enc_b2, nullptr, bufB, NN);
    } else {
        __shared__ int sh[256];
        int t = threadIdx.x;
        int g = (blockIdx.x - gb) * 256 + t;
        int v = (g < NN) ? cnt[g] : 0;
        if (g < NN) dinv[g] = rsqrtf((float)(v + 1));  // +1 self-loop
        sh[t] = v; __syncthreads();
        for (int d = 1; d < 256; d <<= 1) {
            int x2 = (t >= d) ? sh[t - d] : 0; __syncthreads();
            sh[t] += x2; __syncthreads();
        }
        if (g < NN) off[g] = sh[t] - v;
        if (t == 255) bsum[blockIdx.x - gb] = sh[255];
    }
}

// ---------- K4: conv1-mgemm ∥ CSR fill ----------
__global__ __launch_bounds__(256) void k4_k(
    const unsigned short* __restrict__ bufB, const unsigned short* __restrict__ t2,
    const float* __restrict__ dinv, unsigned short* __restrict__ bufA,
    const int* __restrict__ src, const int* __restrict__ dst,
    const int* __restrict__ off, const int* __restrict__ bsum,
    int* __restrict__ cur, unsigned short* __restrict__ csr, int gb)
{
    if ((int)blockIdx.x < gb) {
        mgemm_dev<128, 128, 0, false, true, false, false>(blockIdx.x, bufB, t2, nullptr, dinv, bufA, NN);
    } else {
        int g = (blockIdx.x - gb) * 256 + threadIdx.x;
        if (g < NE) {
            int d = dst[g];
            int p = atomicAdd(&cur[d], 1);
            csr[off[d] + bsum[d >> 8] + p] = (unsigned short)src[g];
        }
    }
}

// ---------- GCN aggregation, feature-split ----------
// HALF selects features [HALF*64, HALF*64+64) = 128 B of each row.
// Quarter-wave (16 lanes) per node; lane owns 4 features as uint2 (bf16x4).
// Two serialized dispatches per conv halve the gather working set (12.8->6.4 MB)
// to raise per-XCD L2 hit rate.
template <int HALF>
__global__ __launch_bounds__(256) void aggh_k(
    const uint2* __restrict__ hws,  // [N][32] uint2 (full rows)
    const int* __restrict__ off, const int* __restrict__ bsum,
    const unsigned short* __restrict__ csr,
    const float* __restrict__ dinv, const float* __restrict__ bias,
    uint2* __restrict__ out, int n)
{
    int node = blockIdx.x * 16 + (threadIdx.x >> 4);
    if (node >= n) return;
    int l = threadIdx.x & 15;

    uint2 v = hws[node * 32 + HALF * 16 + l];  // self-loop term
    float s0 = bflo(v.x), s1 = bfhi(v.x), s2 = bflo(v.y), s3 = bfhi(v.y);

    int b = off[node] + bsum[node >> 8];
    int e = (node + 1 < n) ? (off[node + 1] + bsum[(node + 1) >> 8]) : NE;
    int j = b;
    for (; j + 8 <= e; j += 8) {
        uint2 t[8];
        #pragma unroll
        for (int u = 0; u < 8; u++) t[u] = hws[(int)csr[j + u] * 32 + HALF * 16 + l];
        #pragma unroll
        for (int u = 0; u < 8; u++) {
            s0 += bflo(t[u].x); s1 += bfhi(t[u].x);
            s2 += bflo(t[u].y); s3 += bfhi(t[u].y);
        }
    }
    for (; j < e; j++) {
        uint2 t = hws[(int)csr[j] * 32 + HALF * 16 + l];
        s0 += bflo(t.x); s1 += bfhi(t.x);
        s2 += bflo(t.y); s3 += bfhi(t.y);
    }

    float di = dinv[node];
    float4 bv = *(const float4*)(bias + HALF * 64 + 4 * l);
    float r0 = fmaxf(fmaf(di, s0, bv.x), 0.f);
    float r1 = fmaxf(fmaf(di, s1, bv.y), 0.f);
    float r2 = fmaxf(fmaf(di, s2, bv.z), 0.f);
    float r3 = fmaxf(fmaf(di, s3, bv.w), 0.f);
    uint2 o; o.x = pack2(r0, r1); o.y = pack2(r2, r3);
    out[node * 32 + HALF * 16 + l] = o;
}

// ---------- launch ----------
extern "C" void kernel_launch(void* const* d_in, const int* in_sizes, int n_in,
                              void* d_out, int out_size, void* d_ws, size_t ws_size,
                              hipStream_t stream)
{
    const float* x      = (const float*)d_in[0];
    const int*   ei     = (const int*)d_in[1];
    const float* enc_w1 = (const float*)d_in[2];
    const float* enc_b1 = (const float*)d_in[3];
    const float* enc_w2 = (const float*)d_in[4];
    const float* enc_b2 = (const float*)d_in[5];
    const float* w_c1   = (const float*)d_in[6];
    const float* b_c1   = (const float*)d_in[7];
    const float* w_c2   = (const float*)d_in[8];
    const float* b_c2   = (const float*)d_in[9];
    const float* w_c3   = (const float*)d_in[10];
    const float* b_c3   = (const float*)d_in[11];
    const float* dec_w1 = (const float*)d_in[12];
    const float* dec_b1 = (const float*)d_in[13];
    const float* dec_w2 = (const float*)d_in[14];
    const float* dec_b2 = (const float*)d_in[15];

    const int* src = ei;
    const int* dst = ei + NE;

    const int NP = 50048;  // rows padded to multiple of 64

    char* ws = (char*)d_ws;
    size_t o = 0;
    auto alloc = [&](size_t bytes) -> void* {
        void* p = ws + o;
        o = (o + bytes + 255) & ~(size_t)255;
        return p;
    };
    int*   cnt  = (int*)alloc((size_t)NN * 4);   // cnt and cur adjacent: one memset
    int*   cur  = (int*)alloc((size_t)NN * 4);
    int*   off  = (int*)alloc((size_t)(NN + 1) * 4);
    int*   bsum = (int*)alloc(256 * 4);
    unsigned short* csr = (unsigned short*)alloc((size_t)NE * 2);
    float* dinv = (float*)alloc((size_t)NN * 4);
    unsigned short* bufA = (unsigned short*)alloc((size_t)NP * HD * 2);
    unsigned short* bufB = (unsigned short*)alloc((size_t)NP * HD * 2);
    unsigned short* t0 = (unsigned short*)alloc(64 * 128 * 2);   // enc_w1^T (swizzled)
    unsigned short* t1 = (unsigned short*)alloc(128 * 128 * 2);  // enc_w2^T
    unsigned short* t2 = (unsigned short*)alloc(128 * 128 * 2);  // w_c1^T
    unsigned short* t3 = (unsigned short*)alloc(128 * 128 * 2);  // w_c2^T
    unsigned short* t4 = (unsigned short*)alloc(128 * 128 * 2);  // w_c3^T
    unsigned short* t5 = (unsigned short*)alloc(128 * 128 * 2);  // dec_w1^T
    unsigned short* t6 = (unsigned short*)alloc(128 * 64 * 2);   // dec_w2^T
    (void)ws_size; (void)n_in; (void)in_sizes; (void)out_size;

    // single memset covers cnt + cur (adjacent, 256-aligned)
    hipMemsetAsync(cnt, 0, (size_t)((char*)cur - (char*)cnt) + (size_t)NN * 4, stream);

    const int HB = (NE + 255) / 256;   // 3125 edge blocks
    const int NB_ = (NN + 255) / 256;  // 196 node blocks
    const int GB = NP / 64;            // 782 gemm row-tiles
    const int AH = (NN + 15) / 16;     // 3125 agg-half blocks

    // prep chain overlapped with encoder chain via block-range merged kernels
    wt_k<<<384, 256, 0, stream>>>(enc_w1, enc_w2, w_c1, w_c2, w_c3, dec_w1, dec_w2,
                                  t0, t1, t2, t3, t4, t5, t6);
    k1_k<<<GB + HB, 256, 0, stream>>>(x, t0, enc_b1, bufA, dst, cnt, GB);          // enc1 ∥ hist
    k2_k<<<GB + NB_, 256, 0, stream>>>(bufA, t1, enc_b2, bufB, cnt, off, bsum, dinv, GB); // enc2 ∥ scanA
    scanB_k<<<1, 256, 0, stream>>>(bsum, NB_);
    k4_k<<<GB + HB, 256, 0, stream>>>(bufB, t2, dinv, bufA, src, dst, off, bsum, cur, csr, GB); // conv1 ∥ fill

    // conv1 agg (feature-split)
    aggh_k<0><<<AH, 256, 0, stream>>>((const uint2*)bufA, off, bsum, csr, dinv, b_c1, (uint2*)bufB, NN);
    aggh_k<1><<<AH, 256, 0, stream>>>((const uint2*)bufA, off, bsum, csr, dinv, b_c1, (uint2*)bufB, NN);
    // conv2
    mgemm_k<128, 128, 0, false, true, false, false><<<GB, 256, 0, stream>>>(bufB, t3, nullptr, dinv, bufA, NN);
    aggh_k<0><<<AH, 256, 0, stream>>>((const uint2*)bufA, off, bsum, csr, dinv, b_c2, (uint2*)bufB, NN);
    aggh_k<1><<<AH, 256, 0, stream>>>((const uint2*)bufA, off, bsum, csr, dinv, b_c2, (uint2*)bufB, NN);
    // conv3
    mgemm_k<128, 128, 0, false, true, false, false><<<GB, 256, 0, stream>>>(bufB, t4, nullptr, dinv, bufA, NN);
    aggh_k<0><<<AH, 256, 0, stream>>>((const uint2*)bufA, off, bsum, csr, dinv, b_c3, (uint2*)bufB, NN);
    aggh_k<1><<<AH, 256, 0, stream>>>((const uint2*)bufA, off, bsum, csr, dinv, b_c3, (uint2*)bufB, NN);
    // decoder
    mgemm_k<128, 128, 1, true, false, false, false><<<GB, 256, 0, stream>>>(bufB, t5, dec_b1, nullptr, bufA, NN);
    mgemm_k<128, 64, 2, true, false, false, true><<<GB, 256, 0, stream>>>(bufA, t6, dec_b2, nullptr, d_out, NN);
}

// Round 12
// 311.148 us; speedup vs baseline: 1.4500x; 1.1273x over previous
//
#include <hip/hip_runtime.h>
#include <stdint.h>

#define NN 50000
#define NE 800000
#define FD 64
#define HD 128
#define NBKT 196          // (NN+255)/256 coarse buckets
#define BCAP 5120         // per-bucket capacity (avg 4096, +16 sigma)

typedef __attribute__((ext_vector_type(8))) short short8;   // 8 bf16 (4 VGPRs)
typedef __attribute__((ext_vector_type(4))) float f32x4;    // MFMA acc

#define AS1 __attribute__((address_space(1)))
#define AS3 __attribute__((address_space(3)))

// ---------- bf16 helpers ----------
__device__ __forceinline__ float bflo(unsigned int v) {
    union { unsigned int u; float f; } c; c.u = v << 16; return c.f;
}
__device__ __forceinline__ float bfhi(unsigned int v) {
    union { unsigned int u; float f; } c; c.u = v & 0xffff0000u; return c.f;
}
__device__ __forceinline__ unsigned short f2bf(float f) {
    union { float f; unsigned int u; } c; c.f = f;
    unsigned int u = c.u;
    return (unsigned short)((u + 0x7fffu + ((u >> 16) & 1u)) >> 16);
}
__device__ __forceinline__ unsigned int pack2(float a, float b) {
    return (unsigned int)f2bf(a) | ((unsigned int)f2bf(b) << 16);
}

// ---------- weight transpose/convert/swizzle: W[K][C] fp32 -> Wt[c][K] bf16 ----------
// 16B-granule XOR swizzle: (k,c) -> T[c*K + ((k>>3) ^ (c & (K/8-1)))*8 + (k&7)]
__global__ void wt_k(const float* __restrict__ w0, const float* __restrict__ w1,
                     const float* __restrict__ w2, const float* __restrict__ w3,
                     const float* __restrict__ w4, const float* __restrict__ w5,
                     const float* __restrict__ w6,
                     unsigned short* __restrict__ t0, unsigned short* __restrict__ t1,
                     unsigned short* __restrict__ t2, unsigned short* __restrict__ t3,
                     unsigned short* __restrict__ t4, unsigned short* __restrict__ t5,
                     unsigned short* __restrict__ t6)
{
    int b = blockIdx.x;
    const float* W; unsigned short* T; int K, C;
    if      (b <  32) { W = w0; T = t0; K =  64; C = 128; }
    else if (b <  96) { W = w1; T = t1; K = 128; C = 128; b -= 32; }
    else if (b < 160) { W = w2; T = t2; K = 128; C = 128; b -= 96; }
    else if (b < 224) { W = w3; T = t3; K = 128; C = 128; b -= 160; }
    else if (b < 288) { W = w4; T = t4; K = 128; C = 128; b -= 224; }
    else if (b < 352) { W = w5; T = t5; K = 128; C = 128; b -= 288; }
    else              { W = w6; T = t6; K = 128; C =  64; b -= 352; }
    int e = b * 256 + threadIdx.x;
    int k, c;
    if (C == 128) { k = e >> 7; c = e & 127; } else { k = e >> 6; c = e & 63; }
    int gmask = (K >> 3) - 1;
    int gsw = (k >> 3) ^ (c & gmask);
    T[c * K + gsw * 8 + (k & 7)] = f2bf(W[e]);
}

__global__ void scanB_k(int* __restrict__ bsum, int nb) {
    __shared__ int sh[256];
    int t = threadIdx.x;
    int v = (t < nb) ? bsum[t] : 0;
    sh[t] = v; __syncthreads();
    for (int d = 1; d < 256; d <<= 1) {
        int x = (t >= d) ? sh[t - d] : 0; __syncthreads();
        sh[t] += x; __syncthreads();
    }
    if (t < nb) bsum[t] = sh[t] - v;
}

// ---------- MFMA GEMM device body (block id passed in) ----------
template <int K, int COLS, int EPI, bool BIAS, bool RSCALE, bool A_F32, bool OUT_F32>
__device__ __forceinline__ void mgemm_dev(
    int bid,
    const void* __restrict__ Av,
    const unsigned short* __restrict__ Wt,
    const float* __restrict__ bias,
    const float* __restrict__ dinv,
    void* __restrict__ outv, int nrows)
{
    constexpr int NB = COLS / 16;
    constexpr int KC = K / 32;
    constexpr int GMASK = (K >> 3) - 1;
    __shared__ __align__(16) unsigned char Ws8[COLS * K * 2];

    const int tid = threadIdx.x;
    const int wave = tid >> 6;
    const int lane = tid & 63;

    {
        constexpr int ROUNDS = COLS * K * 2 / 4096;
        const int gb = wave * 1024 + lane * 16;
        const int lb = wave * 1024;
        #pragma unroll
        for (int r = 0; r < ROUNDS; r++) {
            __builtin_amdgcn_global_load_lds(
                (const AS1 unsigned int*)((const unsigned char*)Wt + r * 4096 + gb),
                (AS3 unsigned int*)(Ws8 + r * 4096 + lb),
                16, 0, 0);
        }
    }

    const int m = lane & 15;
    const int q = lane >> 4;
    const int row0 = bid * 64 + wave * 16;

    f32x4 acc[NB];
    #pragma unroll
    for (int i = 0; i < NB; i++) acc[i] = (f32x4){0.f, 0.f, 0.f, 0.f};

    const bool arow_ok = !A_F32 || (row0 + m) < nrows;

    short8 af[KC];
    #pragma unroll
    for (int kc = 0; kc < KC; kc++) {
        if constexpr (A_F32) {
            const float* arowf = (const float*)Av + (size_t)(row0 + m) * K + q * 8 + kc * 32;
            float4 lo = make_float4(0.f, 0.f, 0.f, 0.f), hi = lo;
            if (arow_ok) { lo = *(const float4*)arowf; hi = *(const float4*)(arowf + 4); }
            af[kc][0] = (short)f2bf(lo.x); af[kc][1] = (short)f2bf(lo.y);
            af[kc][2] = (short)f2bf(lo.z); af[kc][3] = (short)f2bf(lo.w);
            af[kc][4] = (short)f2bf(hi.x); af[kc][5] = (short)f2bf(hi.y);
            af[kc][6] = (short)f2bf(hi.z); af[kc][7] = (short)f2bf(hi.w);
        } else {
            const unsigned short* arow = (const unsigned short*)Av + (size_t)(row0 + m) * K + q * 8 + kc * 32;
            af[kc] = *(const short8*)arow;
        }
    }
    __syncthreads();

    #pragma unroll
    for (int kc = 0; kc < KC; kc++) {
        #pragma unroll
        for (int nb = 0; nb < NB; nb++) {
            const int c = nb * 16 + m;
            const int gsw = (kc * 4 + q) ^ (c & GMASK);
            short8 bf = *(const short8*)&Ws8[(c * K + gsw * 8) * 2];
            acc[nb] = __builtin_amdgcn_mfma_f32_16x16x32_bf16(af[kc], bf, acc[nb], 0, 0, 0);
        }
    }

    float bv[NB];
    #pragma unroll
    for (int nb = 0; nb < NB; nb++) bv[nb] = BIAS ? bias[nb * 16 + m] : 0.f;

    #pragma unroll
    for (int r = 0; r < 4; r++) {
        int row = row0 + q * 4 + r;
        if (row < nrows) {
            float sc = RSCALE ? dinv[row] : 1.f;
            #pragma unroll
            for (int nb = 0; nb < NB; nb++) {
                float t = acc[nb][r];
                if (RSCALE) t *= sc;
                t += bv[nb];
                if (EPI == 1) t = fmaxf(t, 0.f);
                if (EPI == 2) t = 1.f / (1.f + __expf(-t));
                if constexpr (OUT_F32) {
                    ((float*)outv)[(size_t)row * COLS + nb * 16 + m] = t;
                } else {
                    ((unsigned short*)outv)[(size_t)row * COLS + nb * 16 + m] = f2bf(t);
                }
            }
        }
    }
}

// plain mgemm wrapper
template <int K, int COLS, int EPI, bool BIAS, bool RSCALE, bool A_F32, bool OUT_F32>
__global__ __launch_bounds__(256) void mgemm_k(
    const void* __restrict__ Av, const unsigned short* __restrict__ Wt,
    const float* __restrict__ bias, const float* __restrict__ dinv,
    void* __restrict__ outv, int nrows)
{
    mgemm_dev<K, COLS, EPI, BIAS, RSCALE, A_F32, OUT_F32>(blockIdx.x, Av, Wt, bias, dinv, outv, nrows);
}

// ---------- K1: enc1-mgemm ∥ (edge hist + coarse bucket sort pass 1) ----------
// pass1: block bins 2048 edges into NBKT buckets (dst>>8). LDS counts ->
// one global reservation per (block,bucket) -> contiguous per-bucket runs.
// Entry pack: src(16b) | dlow(8b)<<16 | bkt(8b)<<24.
__global__ __launch_bounds__(256) void k1_k(
    const float* __restrict__ x, const unsigned short* __restrict__ t0,
    const float* __restrict__ enc_b1, unsigned short* __restrict__ bufA,
    const int* __restrict__ src, const int* __restrict__ dst,
    int* __restrict__ cnt, int* __restrict__ gcnt,
    unsigned int* __restrict__ bucket, int gb)
{
    if ((int)blockIdx.x < gb) {
        mgemm_dev<64, 128, 1, true, false, true, false>(blockIdx.x, x, t0, enc_b1, nullptr, bufA, NN);
    } else {
        __shared__ int lcnt[NBKT], lofs[NBKT];
        const int tid = threadIdx.x;
        const int bb = blockIdx.x - gb;
        if (tid < NBKT) lcnt[tid] = 0;
        __syncthreads();
        unsigned int ent[8];
        #pragma unroll
        for (int u = 0; u < 8; u++) {
            int g = bb * 2048 + u * 256 + tid;
            if (g < NE) {
                int d = dst[g], s = src[g];
                atomicAdd(&cnt[d], 1);                    // node histogram
                int bk = d >> 8;
                atomicAdd(&lcnt[bk], 1);
                ent[u] = (unsigned int)s | ((unsigned int)(d & 255) << 16)
                       | ((unsigned int)bk << 24);
            } else ent[u] = 0xFFFFFFFFu;
        }
        __syncthreads();
        if (tid < NBKT) lofs[tid] = atomicAdd(&gcnt[tid], lcnt[tid]);
        __syncthreads();
        #pragma unroll
        for (int u = 0; u < 8; u++) {
            if (ent[u] != 0xFFFFFFFFu) {
                int bk = ent[u] >> 24;
                int r = atomicAdd(&lofs[bk], 1);
                bucket[bk * BCAP + r] = ent[u];
            }
        }
    }
}

// ---------- K2: enc2-mgemm ∥ scanA ----------
__global__ __launch_bounds__(256) void k2_k(
    const unsigned short* __restrict__ bufA, const unsigned short* __restrict__ t1,
    const float* __restrict__ enc_b2, unsigned short* __restrict__ bufB,
    const int* __restrict__ cnt, int* __restrict__ off, int* __restrict__ bsum,
    float* __restrict__ dinv, int gb)
{
    if ((int)blockIdx.x < gb) {
        mgemm_dev<128, 128, 0, true, false, false, false>(blockIdx.x, bufA, t1, enc_b2, nullptr, bufB, NN);
    } else {
        __shared__ int sh[256];
        int t = threadIdx.x;
        int g = (blockIdx.x - gb) * 256 + t;
        int v = (g < NN) ? cnt[g] : 0;
        if (g < NN) dinv[g] = rsqrtf((float)(v + 1));  // +1 self-loop
        sh[t] = v; __syncthreads();
        for (int d = 1; d < 256; d <<= 1) {
            int x2 = (t >= d) ? sh[t - d] : 0; __syncthreads();
            sh[t] += x2; __syncthreads();
        }
        if (g < NN) off[g] = sh[t] - v;
        if (t == 255) bsum[blockIdx.x - gb] = sh[255];
    }
}

// ---------- K4: conv1-mgemm ∥ (bucket sort pass 2: fine CSR scatter) ----------
// pass2: one block per bucket; rank entries per node via LDS atomics; all CSR
// stores land in the bucket's contiguous ~8KB segment (single-XCD locality).
__global__ __launch_bounds__(256) void k4_k(
    const unsigned short* __restrict__ bufB, const unsigned short* __restrict__ t2,
    const float* __restrict__ dinv, unsigned short* __restrict__ bufA,
    const int* __restrict__ gcnt, const unsigned int* __restrict__ bucket,
    const int* __restrict__ off, const int* __restrict__ bsum,
    unsigned short* __restrict__ csr, int gb)
{
    if ((int)blockIdx.x < gb) {
        mgemm_dev<128, 128, 0, false, true, false, false>(blockIdx.x, bufB, t2, nullptr, dinv, bufA, NN);
    } else {
        __shared__ int lc[256];
        const int tid = threadIdx.x;
        const int b = blockIdx.x - gb;
        lc[tid] = 0;
        __syncthreads();
        const int cb = gcnt[b];
        const int base = bsum[b];
        for (int i = tid; i < cb; i += 256) {
            unsigned int e = bucket[b * BCAP + i];
            int s = e & 0xffff;
            int dl = (e >> 16) & 255;
            int r = atomicAdd(&lc[dl], 1);
            csr[off[b * 256 + dl] + base + r] = (unsigned short)s;
        }
    }
}

// ---------- GCN aggregation: out[d] = relu(dinv[d]*(hws[d] + sum_in hws[s]) + b) ----------
// half-wave (32 lanes) per node; lane owns features {4l..4l+3} as uint2 (bf16x4)
__global__ __launch_bounds__(256) void agg_k(
    const uint2* __restrict__ hws,  // [N][32] uint2
    const int* __restrict__ off, const int* __restrict__ bsum,
    const unsigned short* __restrict__ csr,
    const float* __restrict__ dinv, const float* __restrict__ bias,
    uint2* __restrict__ out, int n)
{
    int node = blockIdx.x * 8 + (threadIdx.x >> 5);
    if (node >= n) return;
    int lane = threadIdx.x & 31;

    uint2 v = hws[node * 32 + lane];  // self-loop term
    float s0 = bflo(v.x), s1 = bfhi(v.x), s2 = bflo(v.y), s3 = bfhi(v.y);

    int b = off[node] + bsum[node >> 8];
    int e = (node + 1 < n) ? (off[node + 1] + bsum[(node + 1) >> 8]) : NE;
    int j = b;
    for (; j + 8 <= e; j += 8) {
        uint2 t[8];
        #pragma unroll
        for (int u = 0; u < 8; u++) t[u] = hws[(int)csr[j + u] * 32 + lane];
        #pragma unroll
        for (int u = 0; u < 8; u++) {
            s0 += bflo(t[u].x); s1 += bfhi(t[u].x);
            s2 += bflo(t[u].y); s3 += bfhi(t[u].y);
        }
    }
    for (; j < e; j++) {
        uint2 t = hws[(int)csr[j] * 32 + lane];
        s0 += bflo(t.x); s1 += bfhi(t.x);
        s2 += bflo(t.y); s3 += bfhi(t.y);
    }

    float di = dinv[node];
    float4 bv = *(const float4*)(bias + 4 * lane);
    float r0 = fmaxf(fmaf(di, s0, bv.x), 0.f);
    float r1 = fmaxf(fmaf(di, s1, bv.y), 0.f);
    float r2 = fmaxf(fmaf(di, s2, bv.z), 0.f);
    float r3 = fmaxf(fmaf(di, s3, bv.w), 0.f);
    uint2 o; o.x = pack2(r0, r1); o.y = pack2(r2, r3);
    out[node * 32 + lane] = o;
}

// ---------- launch ----------
extern "C" void kernel_launch(void* const* d_in, const int* in_sizes, int n_in,
                              void* d_out, int out_size, void* d_ws, size_t ws_size,
                              hipStream_t stream)
{
    const float* x      = (const float*)d_in[0];
    const int*   ei     = (const int*)d_in[1];
    const float* enc_w1 = (const float*)d_in[2];
    const float* enc_b1 = (const float*)d_in[3];
    const float* enc_w2 = (const float*)d_in[4];
    const float* enc_b2 = (const float*)d_in[5];
    const float* w_c1   = (const float*)d_in[6];
    const float* b_c1   = (const float*)d_in[7];
    const float* w_c2   = (const float*)d_in[8];
    const float* b_c2   = (const float*)d_in[9];
    const float* w_c3   = (const float*)d_in[10];
    const float* b_c3   = (const float*)d_in[11];
    const float* dec_w1 = (const float*)d_in[12];
    const float* dec_b1 = (const float*)d_in[13];
    const float* dec_w2 = (const float*)d_in[14];
    const float* dec_b2 = (const float*)d_in[15];

    const int* src = ei;
    const int* dst = ei + NE;

    const int NP = 50048;  // rows padded to multiple of 64

    char* ws = (char*)d_ws;
    size_t o = 0;
    auto alloc = [&](size_t bytes) -> void* {
        void* p = ws + o;
        o = (o + bytes + 255) & ~(size_t)255;
        return p;
    };
    int*   cnt  = (int*)alloc((size_t)NN * 4);   // cnt and gcnt adjacent: one memset
    int*   gcnt = (int*)alloc(256 * 4);
    int*   off  = (int*)alloc((size_t)(NN + 1) * 4);
    int*   bsum = (int*)alloc(256 * 4);
    unsigned short* csr = (unsigned short*)alloc((size_t)NE * 2);
    unsigned int* bucket = (unsigned int*)alloc((size_t)NBKT * BCAP * 4);  // 4 MB
    float* dinv = (float*)alloc((size_t)NN * 4);
    unsigned short* bufA = (unsigned short*)alloc((size_t)NP * HD * 2);
    unsigned short* bufB = (unsigned short*)alloc((size_t)NP * HD * 2);
    unsigned short* t0 = (unsigned short*)alloc(64 * 128 * 2);   // enc_w1^T (swizzled)
    unsigned short* t1 = (unsigned short*)alloc(128 * 128 * 2);  // enc_w2^T
    unsigned short* t2 = (unsigned short*)alloc(128 * 128 * 2);  // w_c1^T
    unsigned short* t3 = (unsigned short*)alloc(128 * 128 * 2);  // w_c2^T
    unsigned short* t4 = (unsigned short*)alloc(128 * 128 * 2);  // w_c3^T
    unsigned short* t5 = (unsigned short*)alloc(128 * 128 * 2);  // dec_w1^T
    unsigned short* t6 = (unsigned short*)alloc(128 * 64 * 2);   // dec_w2^T
    (void)ws_size; (void)n_in; (void)in_sizes; (void)out_size;

    // single memset covers cnt + gcnt (adjacent, 256-aligned)
    hipMemsetAsync(cnt, 0, (size_t)((char*)gcnt - (char*)cnt) + 256 * 4, stream);

    const int PB = (NE + 2047) / 2048; // 391 pass-1 blocks
    const int NB_ = (NN + 255) / 256;  // 196 node blocks
    const int GB = NP / 64;            // 782 gemm row-tiles
    const int AB = (NN + 7) / 8;       // 6250 agg blocks

    // prep chain overlapped with encoder chain via block-range merged kernels
    wt_k<<<384, 256, 0, stream>>>(enc_w1, enc_w2, w_c1, w_c2, w_c3, dec_w1, dec_w2,
                                  t0, t1, t2, t3, t4, t5, t6);
    k1_k<<<GB + PB, 256, 0, stream>>>(x, t0, enc_b1, bufA, src, dst, cnt, gcnt, bucket, GB); // enc1 ∥ hist+sort1
    k2_k<<<GB + NB_, 256, 0, stream>>>(bufA, t1, enc_b2, bufB, cnt, off, bsum, dinv, GB);    // enc2 ∥ scanA
    scanB_k<<<1, 256, 0, stream>>>(bsum, NB_);
    k4_k<<<GB + NBKT, 256, 0, stream>>>(bufB, t2, dinv, bufA, gcnt, bucket, off, bsum, csr, GB); // conv1 ∥ sort2

    // conv1 agg
    agg_k<<<AB, 256, 0, stream>>>((const uint2*)bufA, off, bsum, csr, dinv, b_c1, (uint2*)bufB, NN);
    // conv2
    mgemm_k<128, 128, 0, false, true, false, false><<<GB, 256, 0, stream>>>(bufB, t3, nullptr, dinv, bufA, NN);
    agg_k<<<AB, 256, 0, stream>>>((const uint2*)bufA, off, bsum, csr, dinv, b_c2, (uint2*)bufB, NN);
    // conv3
    mgemm_k<128, 128, 0, false, true, false, false><<<GB, 256, 0, stream>>>(bufB, t4, nullptr, dinv, bufA, NN);
    agg_k<<<AB, 256, 0, stream>>>((const uint2*)bufA, off, bsum, csr, dinv, b_c3, (uint2*)bufB, NN);
    // decoder
    mgemm_k<128, 128, 1, true, false, false, false><<<GB, 256, 0, stream>>>(bufB, t5, dec_b1, nullptr, bufA, NN);
    mgemm_k<128, 64, 2, true, false, false, true><<<GB, 256, 0, stream>>>(bufA, t6, dec_b2, nullptr, d_out, NN);
}

// Round 13
// 281.077 us; speedup vs baseline: 1.6052x; 1.1070x over previous
//
#include <hip/hip_runtime.h>
#include <stdint.h>

#define NN 50000
#define NE 800000
#define FD 64
#define HD 128
#define NBKT 196          // (NN+255)/256 coarse buckets (256 nodes each)
#define BCAP 5120         // per-bucket capacity (avg 4096, generous slack)
#define P1E 4096          // edges per pass-1 block

typedef __attribute__((ext_vector_type(8))) short short8;   // 8 bf16 (4 VGPRs)
typedef __attribute__((ext_vector_type(4))) float f32x4;    // MFMA acc

#define AS1 __attribute__((address_space(1)))
#define AS3 __attribute__((address_space(3)))

// ---------- bf16 helpers ----------
__device__ __forceinline__ float bflo(unsigned int v) {
    union { unsigned int u; float f; } c; c.u = v << 16; return c.f;
}
__device__ __forceinline__ float bfhi(unsigned int v) {
    union { unsigned int u; float f; } c; c.u = v & 0xffff0000u; return c.f;
}
__device__ __forceinline__ unsigned short f2bf(float f) {
    union { float f; unsigned int u; } c; c.f = f;
    unsigned int u = c.u;
    return (unsigned short)((u + 0x7fffu + ((u >> 16) & 1u)) >> 16);
}
__device__ __forceinline__ unsigned int pack2(float a, float b) {
    return (unsigned int)f2bf(a) | ((unsigned int)f2bf(b) << 16);
}

// ---------- weight transpose/convert/swizzle: W[K][C] fp32 -> Wt[c][K] bf16 ----------
// 16B-granule XOR swizzle: (k,c) -> T[c*K + ((k>>3) ^ (c & (K/8-1)))*8 + (k&7)]
__global__ void wt_k(const float* __restrict__ w0, const float* __restrict__ w1,
                     const float* __restrict__ w2, const float* __restrict__ w3,
                     const float* __restrict__ w4, const float* __restrict__ w5,
                     const float* __restrict__ w6,
                     unsigned short* __restrict__ t0, unsigned short* __restrict__ t1,
                     unsigned short* __restrict__ t2, unsigned short* __restrict__ t3,
                     unsigned short* __restrict__ t4, unsigned short* __restrict__ t5,
                     unsigned short* __restrict__ t6)
{
    int b = blockIdx.x;
    const float* W; unsigned short* T; int K, C;
    if      (b <  32) { W = w0; T = t0; K =  64; C = 128; }
    else if (b <  96) { W = w1; T = t1; K = 128; C = 128; b -= 32; }
    else if (b < 160) { W = w2; T = t2; K = 128; C = 128; b -= 96; }
    else if (b < 224) { W = w3; T = t3; K = 128; C = 128; b -= 160; }
    else if (b < 288) { W = w4; T = t4; K = 128; C = 128; b -= 224; }
    else if (b < 352) { W = w5; T = t5; K = 128; C = 128; b -= 288; }
    else              { W = w6; T = t6; K = 128; C =  64; b -= 352; }
    int e = b * 256 + threadIdx.x;
    int k, c;
    if (C == 128) { k = e >> 7; c = e & 127; } else { k = e >> 6; c = e & 63; }
    int gmask = (K >> 3) - 1;
    int gsw = (k >> 3) ^ (c & gmask);
    T[c * K + gsw * 8 + (k & 7)] = f2bf(W[e]);
}

// exclusive scan of gcnt[nb] -> bsum[nb] (bucket bases)
__global__ void scanB_k(const int* __restrict__ gcnt, int* __restrict__ bsum, int nb) {
    __shared__ int sh[256];
    int t = threadIdx.x;
    int v = (t < nb) ? gcnt[t] : 0;
    sh[t] = v; __syncthreads();
    for (int d = 1; d < 256; d <<= 1) {
        int x = (t >= d) ? sh[t - d] : 0; __syncthreads();
        sh[t] += x; __syncthreads();
    }
    if (t < nb) bsum[t] = sh[t] - v;
}

// ---------- MFMA GEMM device body (block id passed in) ----------
template <int K, int COLS, int EPI, bool BIAS, bool RSCALE, bool A_F32, bool OUT_F32>
__device__ __forceinline__ void mgemm_dev(
    int bid,
    const void* __restrict__ Av,
    const unsigned short* __restrict__ Wt,
    const float* __restrict__ bias,
    const float* __restrict__ dinv,
    void* __restrict__ outv, int nrows)
{
    constexpr int NB = COLS / 16;
    constexpr int KC = K / 32;
    constexpr int GMASK = (K >> 3) - 1;
    __shared__ __align__(16) unsigned char Ws8[COLS * K * 2];

    const int tid = threadIdx.x;
    const int wave = tid >> 6;
    const int lane = tid & 63;

    {
        constexpr int ROUNDS = COLS * K * 2 / 4096;
        const int gb = wave * 1024 + lane * 16;
        const int lb = wave * 1024;
        #pragma unroll
        for (int r = 0; r < ROUNDS; r++) {
            __builtin_amdgcn_global_load_lds(
                (const AS1 unsigned int*)((const unsigned char*)Wt + r * 4096 + gb),
                (AS3 unsigned int*)(Ws8 + r * 4096 + lb),
                16, 0, 0);
        }
    }

    const int m = lane & 15;
    const int q = lane >> 4;
    const int row0 = bid * 64 + wave * 16;

    f32x4 acc[NB];
    #pragma unroll
    for (int i = 0; i < NB; i++) acc[i] = (f32x4){0.f, 0.f, 0.f, 0.f};

    const bool arow_ok = !A_F32 || (row0 + m) < nrows;

    short8 af[KC];
    #pragma unroll
    for (int kc = 0; kc < KC; kc++) {
        if constexpr (A_F32) {
            const float* arowf = (const float*)Av + (size_t)(row0 + m) * K + q * 8 + kc * 32;
            float4 lo = make_float4(0.f, 0.f, 0.f, 0.f), hi = lo;
            if (arow_ok) { lo = *(const float4*)arowf; hi = *(const float4*)(arowf + 4); }
            af[kc][0] = (short)f2bf(lo.x); af[kc][1] = (short)f2bf(lo.y);
            af[kc][2] = (short)f2bf(lo.z); af[kc][3] = (short)f2bf(lo.w);
            af[kc][4] = (short)f2bf(hi.x); af[kc][5] = (short)f2bf(hi.y);
            af[kc][6] = (short)f2bf(hi.z); af[kc][7] = (short)f2bf(hi.w);
        } else {
            const unsigned short* arow = (const unsigned short*)Av + (size_t)(row0 + m) * K + q * 8 + kc * 32;
            af[kc] = *(const short8*)arow;
        }
    }
    __syncthreads();

    #pragma unroll
    for (int kc = 0; kc < KC; kc++) {
        #pragma unroll
        for (int nb = 0; nb < NB; nb++) {
            const int c = nb * 16 + m;
            const int gsw = (kc * 4 + q) ^ (c & GMASK);
            short8 bf = *(const short8*)&Ws8[(c * K + gsw * 8) * 2];
            acc[nb] = __builtin_amdgcn_mfma_f32_16x16x32_bf16(af[kc], bf, acc[nb], 0, 0, 0);
        }
    }

    float bv[NB];
    #pragma unroll
    for (int nb = 0; nb < NB; nb++) bv[nb] = BIAS ? bias[nb * 16 + m] : 0.f;

    #pragma unroll
    for (int r = 0; r < 4; r++) {
        int row = row0 + q * 4 + r;
        if (row < nrows) {
            float sc = RSCALE ? dinv[row] : 1.f;
            #pragma unroll
            for (int nb = 0; nb < NB; nb++) {
                float t = acc[nb][r];
                if (RSCALE) t *= sc;
                t += bv[nb];
                if (EPI == 1) t = fmaxf(t, 0.f);
                if (EPI == 2) t = 1.f / (1.f + __expf(-t));
                if constexpr (OUT_F32) {
                    ((float*)outv)[(size_t)row * COLS + nb * 16 + m] = t;
                } else {
                    ((unsigned short*)outv)[(size_t)row * COLS + nb * 16 + m] = f2bf(t);
                }
            }
        }
    }
}

// plain mgemm wrapper
template <int K, int COLS, int EPI, bool BIAS, bool RSCALE, bool A_F32, bool OUT_F32>
__global__ __launch_bounds__(256) void mgemm_k(
    const void* __restrict__ Av, const unsigned short* __restrict__ Wt,
    const float* __restrict__ bias, const float* __restrict__ dinv,
    void* __restrict__ outv, int nrows)
{
    mgemm_dev<K, COLS, EPI, BIAS, RSCALE, A_F32, OUT_F32>(blockIdx.x, Av, Wt, bias, dinv, outv, nrows);
}

// ---------- K1: enc1-mgemm ∥ counting-sort pass 1 (LDS-staged bucket scatter) ----------
// Entry pack: src(16b) | dlow(8b)<<16 | bkt(8b)<<24. No global histogram.
__global__ __launch_bounds__(256) void k1_k(
    const float* __restrict__ x, const unsigned short* __restrict__ t0,
    const float* __restrict__ enc_b1, unsigned short* __restrict__ bufA,
    const int* __restrict__ src, const int* __restrict__ dst,
    int* __restrict__ gcnt, unsigned int* __restrict__ bucket, int gb)
{
    if ((int)blockIdx.x < gb) {
        mgemm_dev<64, 128, 1, true, false, true, false>(blockIdx.x, x, t0, enc_b1, nullptr, bufA, NN);
    } else {
        __shared__ int lcnt[256], lsw[256], lexc[256], lofs[256], lrank[256];
        __shared__ unsigned int stage[P1E];
        const int tid = threadIdx.x;
        const int bb = blockIdx.x - gb;
        lcnt[tid] = 0; lrank[tid] = 0;
        __syncthreads();
        unsigned int ent[P1E / 256];
        #pragma unroll
        for (int u = 0; u < P1E / 256; u++) {
            int g = bb * P1E + u * 256 + tid;
            if (g < NE) {
                int d = dst[g], s = src[g];
                int bk = d >> 8;
                atomicAdd(&lcnt[bk], 1);
                ent[u] = (unsigned int)s | ((unsigned int)(d & 255) << 16)
                       | ((unsigned int)bk << 24);
            } else ent[u] = 0xFFFFFFFFu;
        }
        __syncthreads();
        int v = lcnt[tid];
        lsw[tid] = v; __syncthreads();
        for (int d = 1; d < 256; d <<= 1) {
            int xx = (tid >= d) ? lsw[tid - d] : 0; __syncthreads();
            lsw[tid] += xx; __syncthreads();
        }
        lexc[tid] = lsw[tid] - v;
        lofs[tid] = (v > 0) ? atomicAdd(&gcnt[tid], v) : 0;
        __syncthreads();
        #pragma unroll
        for (int u = 0; u < P1E / 256; u++) {
            if (ent[u] != 0xFFFFFFFFu) {
                int bk = ent[u] >> 24;
                int r = atomicAdd(&lrank[bk], 1);
                stage[lexc[bk] + r] = ent[u];
            }
        }
        __syncthreads();
        int cb = NE - bb * P1E; if (cb > P1E) cb = P1E;
        for (int i = tid; i < cb; i += 256) {
            unsigned int e = stage[i];
            int bk = e >> 24;
            bucket[(size_t)bk * BCAP + lofs[bk] + (i - lexc[bk])] = e;
        }
    }
}

// ---------- K2: enc2-mgemm ∥ pass 2 (per-bucket: hist->dinv, scan->off, rank->CSR) ----------
__global__ __launch_bounds__(256) void k2_k(
    const unsigned short* __restrict__ bufA, const unsigned short* __restrict__ t1,
    const float* __restrict__ enc_b2, unsigned short* __restrict__ bufB,
    const int* __restrict__ gcnt, const unsigned int* __restrict__ bucket,
    const int* __restrict__ bsum,
    int* __restrict__ off, float* __restrict__ dinv,
    unsigned short* __restrict__ csr, int gb)
{
    if ((int)blockIdx.x < gb) {
        mgemm_dev<128, 128, 0, true, false, false, false>(blockIdx.x, bufA, t1, enc_b2, nullptr, bufB, NN);
    } else {
        __shared__ int lc[256], sw[256], sexc[256], lr[256];
        const int tid = threadIdx.x;
        const int b = blockIdx.x - gb;
        const int cb = gcnt[b];
        unsigned int ent[BCAP / 256];
        #pragma unroll
        for (int u = 0; u < BCAP / 256; u++) {
            int i = u * 256 + tid;
            ent[u] = (i < cb) ? bucket[(size_t)b * BCAP + i] : 0xFFFFFFFFu;
        }
        lc[tid] = 0; lr[tid] = 0;
        __syncthreads();
        #pragma unroll
        for (int u = 0; u < BCAP / 256; u++)
            if (ent[u] != 0xFFFFFFFFu) atomicAdd(&lc[(ent[u] >> 16) & 255], 1);
        __syncthreads();
        int v = lc[tid];
        int node = b * 256 + tid;
        if (node < NN) dinv[node] = rsqrtf((float)(v + 1));  // +1 self-loop
        sw[tid] = v; __syncthreads();
        for (int d = 1; d < 256; d <<= 1) {
            int xx = (tid >= d) ? sw[tid - d] : 0; __syncthreads();
            sw[tid] += xx; __syncthreads();
        }
        sexc[tid] = sw[tid] - v;
        if (node < NN) off[node] = sexc[tid];
        __syncthreads();
        const int base = bsum[b];
        #pragma unroll
        for (int u = 0; u < BCAP / 256; u++) {
            if (ent[u] != 0xFFFFFFFFu) {
                int dl = (ent[u] >> 16) & 255;
                int r = atomicAdd(&lr[dl], 1);
                csr[base + sexc[dl] + r] = (unsigned short)(ent[u] & 0xffff);
            }
        }
    }
}

// ---------- GCN aggregation: out[d] = relu(dinv[d]*(hws[d] + sum_in hws[s]) + b) ----------
// half-wave (32 lanes) per node; lane owns features {4l..4l+3} as uint2 (bf16x4)
__global__ __launch_bounds__(256) void agg_k(
    const uint2* __restrict__ hws,  // [N][32] uint2
    const int* __restrict__ off, const int* __restrict__ bsum,
    const unsigned short* __restrict__ csr,
    const float* __restrict__ dinv, const float* __restrict__ bias,
    uint2* __restrict__ out, int n)
{
    int node = blockIdx.x * 8 + (threadIdx.x >> 5);
    if (node >= n) return;
    int lane = threadIdx.x & 31;

    uint2 v = hws[node * 32 + lane];  // self-loop term
    float s0 = bflo(v.x), s1 = bfhi(v.x), s2 = bflo(v.y), s3 = bfhi(v.y);

    int b = off[node] + bsum[node >> 8];
    int e = (node + 1 < n) ? (off[node + 1] + bsum[(node + 1) >> 8]) : NE;
    int j = b;
    for (; j + 8 <= e; j += 8) {
        uint2 t[8];
        #pragma unroll
        for (int u = 0; u < 8; u++) t[u] = hws[(int)csr[j + u] * 32 + lane];
        #pragma unroll
        for (int u = 0; u < 8; u++) {
            s0 += bflo(t[u].x); s1 += bfhi(t[u].x);
            s2 += bflo(t[u].y); s3 += bfhi(t[u].y);
        }
    }
    for (; j < e; j++) {
        uint2 t = hws[(int)csr[j] * 32 + lane];
        s0 += bflo(t.x); s1 += bfhi(t.x);
        s2 += bflo(t.y); s3 += bfhi(t.y);
    }

    float di = dinv[node];
    float4 bv = *(const float4*)(bias + 4 * lane);
    float r0 = fmaxf(fmaf(di, s0, bv.x), 0.f);
    float r1 = fmaxf(fmaf(di, s1, bv.y), 0.f);
    float r2 = fmaxf(fmaf(di, s2, bv.z), 0.f);
    float r3 = fmaxf(fmaf(di, s3, bv.w), 0.f);
    uint2 o; o.x = pack2(r0, r1); o.y = pack2(r2, r3);
    out[node * 32 + lane] = o;
}

// ---------- launch ----------
extern "C" void kernel_launch(void* const* d_in, const int* in_sizes, int n_in,
                              void* d_out, int out_size, void* d_ws, size_t ws_size,
                              hipStream_t stream)
{
    const float* x      = (const float*)d_in[0];
    const int*   ei     = (const int*)d_in[1];
    const float* enc_w1 = (const float*)d_in[2];
    const float* enc_b1 = (const float*)d_in[3];
    const float* enc_w2 = (const float*)d_in[4];
    const float* enc_b2 = (const float*)d_in[5];
    const float* w_c1   = (const float*)d_in[6];
    const float* b_c1   = (const float*)d_in[7];
    const float* w_c2   = (const float*)d_in[8];
    const float* b_c2   = (const float*)d_in[9];
    const float* w_c3   = (const float*)d_in[10];
    const float* b_c3   = (const float*)d_in[11];
    const float* dec_w1 = (const float*)d_in[12];
    const float* dec_b1 = (const float*)d_in[13];
    const float* dec_w2 = (const float*)d_in[14];
    const float* dec_b2 = (const float*)d_in[15];

    const int* src = ei;
    const int* dst = ei + NE;

    const int NP = 50048;  // rows padded to multiple of 64

    char* ws = (char*)d_ws;
    size_t o = 0;
    auto alloc = [&](size_t bytes) -> void* {
        void* p = ws + o;
        o = (o + bytes + 255) & ~(size_t)255;
        return p;
    };
    int*   gcnt = (int*)alloc(256 * 4);
    int*   off  = (int*)alloc((size_t)(NN + 1) * 4);
    int*   bsum = (int*)alloc(256 * 4);
    unsigned short* csr = (unsigned short*)alloc((size_t)NE * 2);
    unsigned int* bucket = (unsigned int*)alloc((size_t)NBKT * BCAP * 4);  // 4 MB
    float* dinv = (float*)alloc((size_t)NN * 4);
    unsigned short* bufA = (unsigned short*)alloc((size_t)NP * HD * 2);
    unsigned short* bufB = (unsigned short*)alloc((size_t)NP * HD * 2);
    unsigned short* t0 = (unsigned short*)alloc(64 * 128 * 2);   // enc_w1^T (swizzled)
    unsigned short* t1 = (unsigned short*)alloc(128 * 128 * 2);  // enc_w2^T
    unsigned short* t2 = (unsigned short*)alloc(128 * 128 * 2);  // w_c1^T
    unsigned short* t3 = (unsigned short*)alloc(128 * 128 * 2);  // w_c2^T
    unsigned short* t4 = (unsigned short*)alloc(128 * 128 * 2);  // w_c3^T
    unsigned short* t5 = (unsigned short*)alloc(128 * 128 * 2);  // dec_w1^T
    unsigned short* t6 = (unsigned short*)alloc(128 * 64 * 2);   // dec_w2^T
    (void)ws_size; (void)n_in; (void)in_sizes; (void)out_size;

    hipMemsetAsync(gcnt, 0, 256 * 4, stream);

    const int PB = (NE + P1E - 1) / P1E;  // 196 pass-1 blocks
    const int GB = NP / 64;               // 782 gemm row-tiles
    const int AB = (NN + 7) / 8;          // 6250 agg blocks

    wt_k<<<384, 256, 0, stream>>>(enc_w1, enc_w2, w_c1, w_c2, w_c3, dec_w1, dec_w2,
                                  t0, t1, t2, t3, t4, t5, t6);
    // enc1 ∥ counting-sort pass 1
    k1_k<<<GB + PB, 256, 0, stream>>>(x, t0, enc_b1, bufA, src, dst, gcnt, bucket, GB);
    scanB_k<<<1, 256, 0, stream>>>(gcnt, bsum, NBKT);
    // enc2 ∥ pass 2 (dinv + off + CSR)
    k2_k<<<GB + NBKT, 256, 0, stream>>>(bufA, t1, enc_b2, bufB, gcnt, bucket, bsum,
                                        off, dinv, csr, GB);
    // conv1
    mgemm_k<128, 128, 0, false, true, false, false><<<GB, 256, 0, stream>>>(bufB, t2, nullptr, dinv, bufA, NN);
    agg_k<<<AB, 256, 0, stream>>>((const uint2*)bufA, off, bsum, csr, dinv, b_c1, (uint2*)bufB, NN);
    // conv2
    mgemm_k<128, 128, 0, false, true, false, false><<<GB, 256, 0, stream>>>(bufB, t3, nullptr, dinv, bufA, NN);
    agg_k<<<AB, 256, 0, stream>>>((const uint2*)bufA, off, bsum, csr, dinv, b_c2, (uint2*)bufB, NN);
    // conv3
    mgemm_k<128, 128, 0, false, true, false, false><<<GB, 256, 0, stream>>>(bufB, t4, nullptr, dinv, bufA, NN);
    agg_k<<<AB, 256, 0, stream>>>((const uint2*)bufA, off, bsum, csr, dinv, b_c3, (uint2*)bufB, NN);
    // decoder
    mgemm_k<128, 128, 1, true, false, false, false><<<GB, 256, 0, stream>>>(bufB, t5, dec_b1, nullptr, bufA, NN);
    mgemm_k<128, 64, 2, true, false, false, true><<<GB, 256, 0, stream>>>(bufA, t6, dec_b2, nullptr, d_out, NN);
}

// Round 14
// 280.725 us; speedup vs baseline: 1.6072x; 1.0013x over previous
//
#include <hip/hip_runtime.h>
#include <stdint.h>

#define NN 50000
#define NE 800000
#define FD 64
#define HD 128
#define NBKT 196          // (NN+255)/256 coarse buckets (256 nodes each)
#define BCAP 5120         // per-bucket capacity (avg 4096, generous slack)
#define P1E 8192          // edges per pass-1 block

typedef __attribute__((ext_vector_type(8))) short short8;   // 8 bf16 (4 VGPRs)
typedef __attribute__((ext_vector_type(4))) float f32x4;    // MFMA acc

#define AS1 __attribute__((address_space(1)))
#define AS3 __attribute__((address_space(3)))

// ---------- bf16 helpers ----------
__device__ __forceinline__ float bflo(unsigned int v) {
    union { unsigned int u; float f; } c; c.u = v << 16; return c.f;
}
__device__ __forceinline__ float bfhi(unsigned int v) {
    union { unsigned int u; float f; } c; c.u = v & 0xffff0000u; return c.f;
}
__device__ __forceinline__ unsigned short f2bf(float f) {
    union { float f; unsigned int u; } c; c.f = f;
    unsigned int u = c.u;
    return (unsigned short)((u + 0x7fffu + ((u >> 16) & 1u)) >> 16);
}
__device__ __forceinline__ unsigned int pack2(float a, float b) {
    return (unsigned int)f2bf(a) | ((unsigned int)f2bf(b) << 16);
}

// ---------- t0 transpose/convert/swizzle: enc_w1[64][128] fp32 -> t0[c][64] bf16 ----------
__global__ void wt0_k(const float* __restrict__ w0, unsigned short* __restrict__ t0) {
    int e = blockIdx.x * 256 + threadIdx.x;   // 32 blocks
    int k = e >> 7, c = e & 127;
    int gsw = (k >> 3) ^ (c & 7);             // K=64 -> gmask 7
    t0[c * 64 + gsw * 8 + (k & 7)] = f2bf(w0[e]);
}

// ---------- MFMA GEMM device body (block id passed in) ----------
template <int K, int COLS, int EPI, bool BIAS, bool RSCALE, bool A_F32, bool OUT_F32>
__device__ __forceinline__ void mgemm_dev(
    int bid,
    const void* __restrict__ Av,
    const unsigned short* __restrict__ Wt,
    const float* __restrict__ bias,
    const float* __restrict__ dinv,
    void* __restrict__ outv, int nrows)
{
    constexpr int NB = COLS / 16;
    constexpr int KC = K / 32;
    constexpr int GMASK = (K >> 3) - 1;
    __shared__ __align__(16) unsigned char Ws8[COLS * K * 2];

    const int tid = threadIdx.x;
    const int wave = tid >> 6;
    const int lane = tid & 63;

    {
        constexpr int ROUNDS = COLS * K * 2 / 4096;
        const int gb = wave * 1024 + lane * 16;
        const int lb = wave * 1024;
        #pragma unroll
        for (int r = 0; r < ROUNDS; r++) {
            __builtin_amdgcn_global_load_lds(
                (const AS1 unsigned int*)((const unsigned char*)Wt + r * 4096 + gb),
                (AS3 unsigned int*)(Ws8 + r * 4096 + lb),
                16, 0, 0);
        }
    }

    const int m = lane & 15;
    const int q = lane >> 4;
    const int row0 = bid * 64 + wave * 16;

    f32x4 acc[NB];
    #pragma unroll
    for (int i = 0; i < NB; i++) acc[i] = (f32x4){0.f, 0.f, 0.f, 0.f};

    const bool arow_ok = !A_F32 || (row0 + m) < nrows;

    short8 af[KC];
    #pragma unroll
    for (int kc = 0; kc < KC; kc++) {
        if constexpr (A_F32) {
            const float* arowf = (const float*)Av + (size_t)(row0 + m) * K + q * 8 + kc * 32;
            float4 lo = make_float4(0.f, 0.f, 0.f, 0.f), hi = lo;
            if (arow_ok) { lo = *(const float4*)arowf; hi = *(const float4*)(arowf + 4); }
            af[kc][0] = (short)f2bf(lo.x); af[kc][1] = (short)f2bf(lo.y);
            af[kc][2] = (short)f2bf(lo.z); af[kc][3] = (short)f2bf(lo.w);
            af[kc][4] = (short)f2bf(hi.x); af[kc][5] = (short)f2bf(hi.y);
            af[kc][6] = (short)f2bf(hi.z); af[kc][7] = (short)f2bf(hi.w);
        } else {
            const unsigned short* arow = (const unsigned short*)Av + (size_t)(row0 + m) * K + q * 8 + kc * 32;
            af[kc] = *(const short8*)arow;
        }
    }
    __syncthreads();

    #pragma unroll
    for (int kc = 0; kc < KC; kc++) {
        #pragma unroll
        for (int nb = 0; nb < NB; nb++) {
            const int c = nb * 16 + m;
            const int gsw = (kc * 4 + q) ^ (c & GMASK);
            short8 bf = *(const short8*)&Ws8[(c * K + gsw * 8) * 2];
            acc[nb] = __builtin_amdgcn_mfma_f32_16x16x32_bf16(af[kc], bf, acc[nb], 0, 0, 0);
        }
    }

    float bv[NB];
    #pragma unroll
    for (int nb = 0; nb < NB; nb++) bv[nb] = BIAS ? bias[nb * 16 + m] : 0.f;

    #pragma unroll
    for (int r = 0; r < 4; r++) {
        int row = row0 + q * 4 + r;
        if (row < nrows) {
            float sc = RSCALE ? dinv[row] : 1.f;
            #pragma unroll
            for (int nb = 0; nb < NB; nb++) {
                float t = acc[nb][r];
                if (RSCALE) t *= sc;
                t += bv[nb];
                if (EPI == 1) t = fmaxf(t, 0.f);
                if (EPI == 2) t = 1.f / (1.f + __expf(-t));
                if constexpr (OUT_F32) {
                    ((float*)outv)[(size_t)row * COLS + nb * 16 + m] = t;
                } else {
                    ((unsigned short*)outv)[(size_t)row * COLS + nb * 16 + m] = f2bf(t);
                }
            }
        }
    }
}

// plain mgemm wrapper
template <int K, int COLS, int EPI, bool BIAS, bool RSCALE, bool A_F32, bool OUT_F32>
__global__ __launch_bounds__(256) void mgemm_k(
    const void* __restrict__ Av, const unsigned short* __restrict__ Wt,
    const float* __restrict__ bias, const float* __restrict__ dinv,
    void* __restrict__ outv, int nrows)
{
    mgemm_dev<K, COLS, EPI, BIAS, RSCALE, A_F32, OUT_F32>(blockIdx.x, Av, Wt, bias, dinv, outv, nrows);
}

// ---------- K1: enc1-mgemm ∥ counting-sort pass 1 ∥ t1-t6 transposes ----------
// Entry pack: src(16b) | dlow(8b)<<16 | bkt(8b)<<24.
__global__ __launch_bounds__(256) void k1_k(
    const float* __restrict__ x, const unsigned short* __restrict__ t0s,
    const float* __restrict__ enc_b1, unsigned short* __restrict__ bufA,
    const int* __restrict__ src, const int* __restrict__ dst,
    int* __restrict__ gcnt, unsigned int* __restrict__ bucket,
    const float* __restrict__ w1, const float* __restrict__ w2,
    const float* __restrict__ w3, const float* __restrict__ w4,
    const float* __restrict__ w5, const float* __restrict__ w6,
    unsigned short* __restrict__ t1, unsigned short* __restrict__ t2,
    unsigned short* __restrict__ t3, unsigned short* __restrict__ t4,
    unsigned short* __restrict__ t5, unsigned short* __restrict__ t6,
    int gb, int pb)
{
    const int b = blockIdx.x;
    if (b < gb) {
        mgemm_dev<64, 128, 1, true, false, true, false>(b, x, t0s, enc_b1, nullptr, bufA, NN);
    } else if (b < gb + pb) {
        __shared__ int lcnt[256], lsw[256], lexc[256], lofs[256], lrank[256];
        __shared__ unsigned int stage[P1E];
        const int tid = threadIdx.x;
        const int bb = b - gb;
        lcnt[tid] = 0; lrank[tid] = 0;
        __syncthreads();
        unsigned int ent[P1E / 256];
        #pragma unroll
        for (int u = 0; u < P1E / 256; u++) {
            int g = bb * P1E + u * 256 + tid;
            if (g < NE) {
                int d = dst[g], s = src[g];
                int bk = d >> 8;
                atomicAdd(&lcnt[bk], 1);
                ent[u] = (unsigned int)s | ((unsigned int)(d & 255) << 16)
                       | ((unsigned int)bk << 24);
            } else ent[u] = 0xFFFFFFFFu;
        }
        __syncthreads();
        int v = lcnt[tid];
        lsw[tid] = v; __syncthreads();
        for (int d = 1; d < 256; d <<= 1) {
            int xx = (tid >= d) ? lsw[tid - d] : 0; __syncthreads();
            lsw[tid] += xx; __syncthreads();
        }
        lexc[tid] = lsw[tid] - v;
        lofs[tid] = (v > 0) ? atomicAdd(&gcnt[tid], v) : 0;
        __syncthreads();
        #pragma unroll
        for (int u = 0; u < P1E / 256; u++) {
            if (ent[u] != 0xFFFFFFFFu) {
                int bk = ent[u] >> 24;
                int r = atomicAdd(&lrank[bk], 1);
                stage[lexc[bk] + r] = ent[u];
            }
        }
        __syncthreads();
        int cb = NE - bb * P1E; if (cb > P1E) cb = P1E;
        for (int i = tid; i < cb; i += 256) {
            unsigned int e = stage[i];
            int bk = e >> 24;
            bucket[(size_t)bk * BCAP + lofs[bk] + (i - lexc[bk])] = e;
        }
    } else {
        int b2 = b - gb - pb;       // 352 transpose blocks, all K=128
        const float* W; unsigned short* T; int C = 128;
        if      (b2 <  64) { W = w1; T = t1; }
        else if (b2 < 128) { W = w2; T = t2; b2 -= 64; }
        else if (b2 < 192) { W = w3; T = t3; b2 -= 128; }
        else if (b2 < 256) { W = w4; T = t4; b2 -= 192; }
        else if (b2 < 320) { W = w5; T = t5; b2 -= 256; }
        else               { W = w6; T = t6; b2 -= 320; C = 64; }
        int e = b2 * 256 + threadIdx.x;
        int k, c;
        if (C == 128) { k = e >> 7; c = e & 127; } else { k = e >> 6; c = e & 63; }
        int gsw = (k >> 3) ^ (c & 15);   // K=128 -> gmask 15
        T[c * 128 + gsw * 8 + (k & 7)] = f2bf(W[e]);
    }
}

// ---------- K2: enc2-mgemm ∥ pass 2 (local gcnt scan -> absolute off, dinv, CSR) ----------
__global__ __launch_bounds__(256) void k2_k(
    const unsigned short* __restrict__ bufA, const unsigned short* __restrict__ t1,
    const float* __restrict__ enc_b2, unsigned short* __restrict__ bufB,
    const int* __restrict__ gcnt, const unsigned int* __restrict__ bucket,
    int* __restrict__ off, float* __restrict__ dinv,
    unsigned short* __restrict__ csr, int gb)
{
    if ((int)blockIdx.x < gb) {
        mgemm_dev<128, 128, 0, true, false, false, false>(blockIdx.x, bufA, t1, enc_b2, nullptr, bufB, NN);
    } else {
        __shared__ int lc[256], sw[256], sexc[256], lr[256], gsh[256];
        const int tid = threadIdx.x;
        const int b = blockIdx.x - gb;
        // local exclusive scan of gcnt -> bucket base (uniform)
        int gv = (tid < NBKT) ? gcnt[tid] : 0;
        gsh[tid] = gv; __syncthreads();
        for (int d = 1; d < 256; d <<= 1) {
            int xx = (tid >= d) ? gsh[tid - d] : 0; __syncthreads();
            gsh[tid] += xx; __syncthreads();
        }
        const int cb = gcnt[b];
        const int base = gsh[b] - cb;
        unsigned int ent[BCAP / 256];
        #pragma unroll
        for (int u = 0; u < BCAP / 256; u++) {
            int i = u * 256 + tid;
            ent[u] = (i < cb) ? bucket[(size_t)b * BCAP + i] : 0xFFFFFFFFu;
        }
        lc[tid] = 0; lr[tid] = 0;
        __syncthreads();
        #pragma unroll
        for (int u = 0; u < BCAP / 256; u++)
            if (ent[u] != 0xFFFFFFFFu) atomicAdd(&lc[(ent[u] >> 16) & 255], 1);
        __syncthreads();
        int v = lc[tid];
        int node = b * 256 + tid;
        if (node < NN) dinv[node] = rsqrtf((float)(v + 1));  // +1 self-loop
        sw[tid] = v; __syncthreads();
        for (int d = 1; d < 256; d <<= 1) {
            int xx = (tid >= d) ? sw[tid - d] : 0; __syncthreads();
            sw[tid] += xx; __syncthreads();
        }
        sexc[tid] = sw[tid] - v;
        if (node < NN) off[node] = base + sexc[tid];         // absolute offset
        if (b == NBKT - 1 && tid == 0) off[NN] = NE;
        __syncthreads();
        #pragma unroll
        for (int u = 0; u < BCAP / 256; u++) {
            if (ent[u] != 0xFFFFFFFFu) {
                int dl = (ent[u] >> 16) & 255;
                int r = atomicAdd(&lr[dl], 1);
                csr[base + sexc[dl] + r] = (unsigned short)(ent[u] & 0xffff);
            }
        }
    }
}

// ---------- GCN aggregation: out[d] = relu(dinv[d]*(hws[d] + sum_in hws[s]) + b) ----------
// half-wave (32 lanes) per node; lane owns features {4l..4l+3} as uint2 (bf16x4)
__global__ __launch_bounds__(256) void agg_k(
    const uint2* __restrict__ hws,  // [N][32] uint2
    const int* __restrict__ off,
    const unsigned short* __restrict__ csr,
    const float* __restrict__ dinv, const float* __restrict__ bias,
    uint2* __restrict__ out, int n)
{
    int node = blockIdx.x * 8 + (threadIdx.x >> 5);
    if (node >= n) return;
    int lane = threadIdx.x & 31;

    uint2 v = hws[node * 32 + lane];  // self-loop term
    float s0 = bflo(v.x), s1 = bfhi(v.x), s2 = bflo(v.y), s3 = bfhi(v.y);

    int b = off[node], e = off[node + 1];
    int j = b;
    for (; j + 8 <= e; j += 8) {
        uint2 t[8];
        #pragma unroll
        for (int u = 0; u < 8; u++) t[u] = hws[(int)csr[j + u] * 32 + lane];
        #pragma unroll
        for (int u = 0; u < 8; u++) {
            s0 += bflo(t[u].x); s1 += bfhi(t[u].x);
            s2 += bflo(t[u].y); s3 += bfhi(t[u].y);
        }
    }
    for (; j < e; j++) {
        uint2 t = hws[(int)csr[j] * 32 + lane];
        s0 += bflo(t.x); s1 += bfhi(t.x);
        s2 += bflo(t.y); s3 += bfhi(t.y);
    }

    float di = dinv[node];
    float4 bv = *(const float4*)(bias + 4 * lane);
    float r0 = fmaxf(fmaf(di, s0, bv.x), 0.f);
    float r1 = fmaxf(fmaf(di, s1, bv.y), 0.f);
    float r2 = fmaxf(fmaf(di, s2, bv.z), 0.f);
    float r3 = fmaxf(fmaf(di, s3, bv.w), 0.f);
    uint2 o; o.x = pack2(r0, r1); o.y = pack2(r2, r3);
    out[node * 32 + lane] = o;
}

// ---------- launch ----------
extern "C" void kernel_launch(void* const* d_in, const int* in_sizes, int n_in,
                              void* d_out, int out_size, void* d_ws, size_t ws_size,
                              hipStream_t stream)
{
    const float* x      = (const float*)d_in[0];
    const int*   ei     = (const int*)d_in[1];
    const float* enc_w1 = (const float*)d_in[2];
    const float* enc_b1 = (const float*)d_in[3];
    const float* enc_w2 = (const float*)d_in[4];
    const float* enc_b2 = (const float*)d_in[5];
    const float* w_c1   = (const float*)d_in[6];
    const float* b_c1   = (const float*)d_in[7];
    const float* w_c2   = (const float*)d_in[8];
    const float* b_c2   = (const float*)d_in[9];
    const float* w_c3   = (const float*)d_in[10];
    const float* b_c3   = (const float*)d_in[11];
    const float* dec_w1 = (const float*)d_in[12];
    const float* dec_b1 = (const float*)d_in[13];
    const float* dec_w2 = (const float*)d_in[14];
    const float* dec_b2 = (const float*)d_in[15];

    const int* src = ei;
    const int* dst = ei + NE;

    const int NP = 50048;  // rows padded to multiple of 64

    char* ws = (char*)d_ws;
    size_t o = 0;
    auto alloc = [&](size_t bytes) -> void* {
        void* p = ws + o;
        o = (o + bytes + 255) & ~(size_t)255;
        return p;
    };
    int*   gcnt = (int*)alloc(256 * 4);
    int*   off  = (int*)alloc((size_t)(NN + 1) * 4);
    unsigned short* csr = (unsigned short*)alloc((size_t)NE * 2);
    unsigned int* bucket = (unsigned int*)alloc((size_t)NBKT * BCAP * 4);  // 4 MB
    float* dinv = (float*)alloc((size_t)NN * 4);
    unsigned short* bufA = (unsigned short*)alloc((size_t)NP * HD * 2);
    unsigned short* bufB = (unsigned short*)alloc((size_t)NP * HD * 2);
    unsigned short* t0 = (unsigned short*)alloc(64 * 128 * 2);   // enc_w1^T (swizzled)
    unsigned short* t1 = (unsigned short*)alloc(128 * 128 * 2);  // enc_w2^T
    unsigned short* t2 = (unsigned short*)alloc(128 * 128 * 2);  // w_c1^T
    unsigned short* t3 = (unsigned short*)alloc(128 * 128 * 2);  // w_c2^T
    unsigned short* t4 = (unsigned short*)alloc(128 * 128 * 2);  // w_c3^T
    unsigned short* t5 = (unsigned short*)alloc(128 * 128 * 2);  // dec_w1^T
    unsigned short* t6 = (unsigned short*)alloc(128 * 64 * 2);   // dec_w2^T
    (void)ws_size; (void)n_in; (void)in_sizes; (void)out_size;

    hipMemsetAsync(gcnt, 0, 256 * 4, stream);

    const int PB = (NE + P1E - 1) / P1E;  // 98 pass-1 blocks
    const int GB = NP / 64;               // 782 gemm row-tiles
    const int AB = (NN + 7) / 8;          // 6250 agg blocks

    // t0 first (k1's gemm branch reads it)
    wt0_k<<<32, 256, 0, stream>>>(enc_w1, t0);
    // enc1 ∥ pass 1 ∥ t1-t6 transposes
    k1_k<<<GB + PB + 352, 256, 0, stream>>>(x, t0, enc_b1, bufA, src, dst, gcnt, bucket,
                                            enc_w2, w_c1, w_c2, w_c3, dec_w1, dec_w2,
                                            t1, t2, t3, t4, t5, t6, GB, PB);
    // enc2 ∥ pass 2 (absolute off + dinv + CSR)
    k2_k<<<GB + NBKT, 256, 0, stream>>>(bufA, t1, enc_b2, bufB, gcnt, bucket,
                                        off, dinv, csr, GB);
    // conv1
    mgemm_k<128, 128, 0, false, true, false, false><<<GB, 256, 0, stream>>>(bufB, t2, nullptr, dinv, bufA, NN);
    agg_k<<<AB, 256, 0, stream>>>((const uint2*)bufA, off, csr, dinv, b_c1, (uint2*)bufB, NN);
    // conv2
    mgemm_k<128, 128, 0, false, true, false, false><<<GB, 256, 0, stream>>>(bufB, t3, nullptr, dinv, bufA, NN);
    agg_k<<<AB, 256, 0, stream>>>((const uint2*)bufA, off, csr, dinv, b_c2, (uint2*)bufB, NN);
    // conv3
    mgemm_k<128, 128, 0, false, true, false, false><<<GB, 256, 0, stream>>>(bufB, t4, nullptr, dinv, bufA, NN);
    agg_k<<<AB, 256, 0, stream>>>((const uint2*)bufA, off, csr, dinv, b_c3, (uint2*)bufB, NN);
    // decoder
    mgemm_k<128, 128, 1, true, false, false, false><<<GB, 256, 0, stream>>>(bufB, t5, dec_b1, nullptr, bufA, NN);
    mgemm_k<128, 64, 2, true, false, false, true><<<GB, 256, 0, stream>>>(bufA, t6, dec_b2, nullptr, d_out, NN);
}